// Round 3
// baseline (92390.491 us; speedup 1.0000x reference)
//
#include <hip/hip_runtime.h>
#include <hip/hip_cooperative_groups.h>
#include <cmath>

namespace cg = cooperative_groups;

// HM-LSTM forward, MI355X. Round 2:
//  - ONE persistent cooperative kernel (256 WGs x 512 thr) over all (t,l)
//    stages; cg::this_grid().sync() between stages (vendor fence protocol).
//    z column folded into WG 0 (grid stays at 256 = always co-resident).
//  - Fallback: if hipLaunchCooperativeKernel returns an error, run the
//    proven round-0 path (1536 per-stage launches).
//  - Gate arithmetic order identical to the round-0 validated kernel.
//  - Weights pre-transposed to [col][k] in ws; state [feature][batch],
//    ping-ponged by timestep parity.

#define Hh   256
#define Bb   64
#define Tt   512
#define GC   1025
#define KW   256
#define MATF (GC * KW)          // 262400 floats per transposed matrix

struct Ptrs8 { const float* p[8]; };

__global__ __launch_bounds__(256) void transpose_w(Ptrs8 srcs, float* __restrict__ dst) {
    int k = blockIdx.x;                    // 0..255 (row of source = K index)
    int m = blockIdx.y;                    // 0..7   (matrix)
    const float* __restrict__ src = srcs.p[m];
    float* __restrict__ d = dst + (size_t)m * MATF;
#pragma unroll
    for (int c = 0; c < 5; ++c) {
        int col = c * 256 + threadIdx.x;
        if (col < GC) d[(size_t)col * KW + k] = src[(size_t)k * GC + col];
    }
}

// ---------------------------------------------------------------------------
// Persistent cooperative kernel
// ---------------------------------------------------------------------------
struct PK {
    const float* x;
    const float* W[8];      // transposed: Wb0,Wr0,Wt0, Wb1,Wr1,Wt1, Wb2,Wr2
    const float* bias[3];
    float* hT;              // [2][3][256][64]
    float* cT;              // [2][3][256][64]
    float* zS;              // [2][3][64]
    float* out_h;           // (B,T,768)
    float* out_z;           // (B,T,3)
};

__global__ __launch_bounds__(512, 2) void persistent_kernel(PK P) {
    cg::grid_group gg = cg::this_grid();
    __shared__ float  sred[8][4][64];
    __shared__ double zred[8][3][64];

    const int tid  = threadIdx.x;
    const int lane = tid & 63;    // batch row
    const int wv   = tid >> 6;    // 0..7, K chunk
    const int wg   = blockIdx.x;  // 0..255 = gate column j
    const int k0   = wv * 32;

    for (int t = 0; t < Tt; ++t) {
        const int p = t & 1;
#pragma unroll
        for (int l = 0; l < 3; ++l) {
            const float* __restrict__ h_rd  = P.hT + (size_t)(p * 3 + l) * (Hh * Bb);
            const float* __restrict__ ht_rd = (l < 2) ? P.hT + (size_t)(p * 3 + l + 1) * (Hh * Bb) : nullptr;
            const float* __restrict__ hb_rd = (l > 0) ? P.hT + (size_t)((p ^ 1) * 3 + l - 1) * (Hh * Bb) : nullptr;
            const float* __restrict__ c_rd  = P.cT + (size_t)(p * 3 + l) * (Hh * Bb);
            float*       __restrict__ c_wr  = P.cT + (size_t)((p ^ 1) * 3 + l) * (Hh * Bb);
            const float* __restrict__ z_rd  = P.zS + (size_t)(p * 3 + l) * Bb;
            const float* __restrict__ zb_rd = (l > 0) ? P.zS + (size_t)((p ^ 1) * 3 + l - 1) * Bb : nullptr;
            float*       __restrict__ h_wr  = P.hT + (size_t)((p ^ 1) * 3 + l) * (Hh * Bb);
            float*       __restrict__ z_wr  = P.zS + (size_t)((p ^ 1) * 3 + l) * Bb;
            const float* __restrict__ Wb = P.W[l * 3];
            const float* __restrict__ Wr = P.W[l * 3 + 1];
            const float* __restrict__ Wt = (l < 2) ? P.W[l * 3 + 2] : nullptr;
            const float* __restrict__ bias = P.bias[l];
            const bool hasT = (l < 2);

            // ---- gate columns {j, 256+j, 512+j, 768+j} for WG j ----
            {
                const int j = wg;
                const float zb = (l == 0) ? 1.0f : zb_rd[lane];
                const float zo = z_rd[lane];

                const float* __restrict__ wb0 = Wb + (size_t)(0 * Hh + j) * KW;
                const float* __restrict__ wb1 = Wb + (size_t)(1 * Hh + j) * KW;
                const float* __restrict__ wb2 = Wb + (size_t)(2 * Hh + j) * KW;
                const float* __restrict__ wb3 = Wb + (size_t)(3 * Hh + j) * KW;
                const float* __restrict__ wr0 = Wr + (size_t)(0 * Hh + j) * KW;
                const float* __restrict__ wr1 = Wr + (size_t)(1 * Hh + j) * KW;
                const float* __restrict__ wr2 = Wr + (size_t)(2 * Hh + j) * KW;
                const float* __restrict__ wr3 = Wr + (size_t)(3 * Hh + j) * KW;
                const float* __restrict__ wt0 = hasT ? Wt + (size_t)(0 * Hh + j) * KW : nullptr;
                const float* __restrict__ wt1 = hasT ? Wt + (size_t)(1 * Hh + j) * KW : nullptr;
                const float* __restrict__ wt2 = hasT ? Wt + (size_t)(2 * Hh + j) * KW : nullptr;
                const float* __restrict__ wt3 = hasT ? Wt + (size_t)(3 * Hh + j) * KW : nullptr;

                float a0 = 0.f, a1 = 0.f, a2 = 0.f, a3 = 0.f;

                if (l == 0) {
                    // float4 register preload of this lane's 32 contiguous x
                    // values (bitwise-identical to scalar reads).
                    const float4* __restrict__ xp =
                        (const float4*)(P.x + ((size_t)lane * Tt + t) * Hh + k0);
                    float xr[32];
#pragma unroll
                    for (int q = 0; q < 8; ++q) {
                        float4 v = xp[q];
                        xr[4 * q + 0] = v.x; xr[4 * q + 1] = v.y;
                        xr[4 * q + 2] = v.z; xr[4 * q + 3] = v.w;
                    }
#pragma unroll
                    for (int kk = 0; kk < 32; ++kk) {
                        const int k = k0 + kk;
                        float hbz = xr[kk];       // z_bottom == 1 exactly
                        float hv  = h_rd[k * 64 + lane];
                        a0 += wb0[k] * hbz + wr0[k] * hv;
                        a1 += wb1[k] * hbz + wr1[k] * hv;
                        a2 += wb2[k] * hbz + wr2[k] * hv;
                        a3 += wb3[k] * hbz + wr3[k] * hv;
                        float htz = zo * ht_rd[k * 64 + lane];
                        a0 += wt0[k] * htz;
                        a1 += wt1[k] * htz;
                        a2 += wt2[k] * htz;
                        a3 += wt3[k] * htz;
                    }
                } else {
#pragma unroll 8
                    for (int k = k0; k < k0 + 32; ++k) {
                        float hbz = zb * hb_rd[k * 64 + lane];
                        float hv  = h_rd[k * 64 + lane];
                        a0 += wb0[k] * hbz + wr0[k] * hv;
                        a1 += wb1[k] * hbz + wr1[k] * hv;
                        a2 += wb2[k] * hbz + wr2[k] * hv;
                        a3 += wb3[k] * hbz + wr3[k] * hv;
                        if (hasT) {
                            float htz = zo * ht_rd[k * 64 + lane];
                            a0 += wt0[k] * htz;
                            a1 += wt1[k] * htz;
                            a2 += wt2[k] * htz;
                            a3 += wt3[k] * htz;
                        }
                    }
                }
                sred[wv][0][lane] = a0; sred[wv][1][lane] = a1;
                sred[wv][2][lane] = a2; sred[wv][3][lane] = a3;
                __syncthreads();
                if (tid < 64) {
                    const int b = tid;
                    float s0 = bias[0 * Hh + j];
                    float s1 = bias[1 * Hh + j];
                    float s2 = bias[2 * Hh + j];
                    float s3 = bias[3 * Hh + j];
#pragma unroll
                    for (int v = 0; v < 8; ++v) {
                        s0 += sred[v][0][b]; s1 += sred[v][1][b];
                        s2 += sred[v][2][b]; s3 += sred[v][3][b];
                    }
                    float f = 1.0f / (1.0f + expf(-s0));
                    float i = 1.0f / (1.0f + expf(-s1));
                    float o = 1.0f / (1.0f + expf(-s2));
                    float g = tanhf(s3);
                    float zb_ = (l == 0) ? 1.0f : zb_rd[b];
                    float zo_ = z_rd[b];
                    float c    = c_rd[j * 64 + b];
                    float hold = h_rd[j * 64 + b];
                    float ig   = i * g;
                    float cupd = f * c + ig;
                    // z, zb in {0,1} exactly -> selects == reference arithmetic
                    float cnew = (zo_ != 0.0f) ? ig : ((zb_ != 0.0f) ? cupd : c);
                    float hnew = (zo_ == 0.0f && zb_ == 0.0f) ? hold : (o * tanhf(cnew));
                    c_wr[j * 64 + b] = cnew;
                    h_wr[j * 64 + b] = hnew;
                    P.out_h[((size_t)b * Tt + t) * (3 * Hh) + l * Hh + j] = hnew;
                }
            }

            // ---- z column (col 1024) in fp64, WG 0 only ----
            if (wg == 0) {
                const float* __restrict__ wbz = Wb + (size_t)1024 * KW;
                const float* __restrict__ wrz = Wr + (size_t)1024 * KW;
                const float* __restrict__ wtz = hasT ? Wt + (size_t)1024 * KW : nullptr;
                double aB = 0.0, aR = 0.0, aT = 0.0;
                if (l == 0) {
                    const float4* __restrict__ xp =
                        (const float4*)(P.x + ((size_t)lane * Tt + t) * Hh + k0);
                    float xr[32];
#pragma unroll
                    for (int q = 0; q < 8; ++q) {
                        float4 v = xp[q];
                        xr[4 * q + 0] = v.x; xr[4 * q + 1] = v.y;
                        xr[4 * q + 2] = v.z; xr[4 * q + 3] = v.w;
                    }
#pragma unroll
                    for (int kk = 0; kk < 32; ++kk) {
                        const int k = k0 + kk;
                        aB += (double)wbz[k] * (double)xr[kk];
                        aR += (double)wrz[k] * (double)h_rd[k * 64 + lane];
                        aT += (double)wtz[k] * (double)ht_rd[k * 64 + lane];
                    }
                } else {
#pragma unroll 4
                    for (int k = k0; k < k0 + 32; ++k) {
                        aB += (double)wbz[k] * (double)hb_rd[k * 64 + lane];
                        aR += (double)wrz[k] * (double)h_rd[k * 64 + lane];
                        if (hasT) aT += (double)wtz[k] * (double)ht_rd[k * 64 + lane];
                    }
                }
                zred[wv][0][lane] = aB; zred[wv][1][lane] = aR; zred[wv][2][lane] = aT;
                __syncthreads();
                if (tid < 64) {
                    const int b = tid;
                    double sB = 0.0, sR = 0.0, sT = 0.0;
#pragma unroll
                    for (int v = 0; v < 8; ++v) {
                        sB += zred[v][0][b]; sR += zred[v][1][b]; sT += zred[v][2][b];
                    }
                    double zb_ = (l == 0) ? 1.0 : (double)zb_rd[b];
                    double zo_ = (double)z_rd[b];
                    double s = (double)bias[1024] + zb_ * sB + sR + zo_ * sT;
                    // round(clip((s+1)/2,0,1)) with round-half-even == (s > 0)
                    float znew = (s > 0.0) ? 1.0f : 0.0f;
                    z_wr[b] = znew;
                    P.out_z[((size_t)b * Tt + t) * 3 + l] = znew;
                }
            }

            gg.sync();
        }
    }
}

// ---------------------------------------------------------------------------
// Fallback path: round-0 per-stage kernel (proven correct), used only if the
// cooperative launch is rejected by the runtime.
// ---------------------------------------------------------------------------
struct StageP {
    const float* x;
    const float* Wb;
    const float* Wr;
    const float* Wt;
    const float* bias;
    const float* h_rd;
    const float* ht_rd;
    const float* hb_rd;
    const float* c_rd;
    float*       c_wr;
    const float* z_rd;
    const float* zb_rd;
    float*       h_wr;
    float*       z_wr;
    float*       out_h;
    float*       out_z;
    int          t;
    int          layer;
};

__global__ __launch_bounds__(512) void stage_kernel(StageP P) {
    __shared__ float  sred[8][4][64];
    __shared__ double zred[8][3][64];

    const int tid  = threadIdx.x;
    const int lane = tid & 63;
    const int wv   = tid >> 6;
    const int wg   = blockIdx.x;
    const int t = P.t, l = P.layer;
    const int k0 = wv * 32;

    if (wg < 256) {
        const int j = wg;
        const float zb = (l == 0) ? 1.0f : P.zb_rd[lane];
        const float zo = P.z_rd[lane];
        const bool hasT = (l < 2);

        const float* __restrict__ wb0 = P.Wb + (size_t)(0 * Hh + j) * KW;
        const float* __restrict__ wb1 = P.Wb + (size_t)(1 * Hh + j) * KW;
        const float* __restrict__ wb2 = P.Wb + (size_t)(2 * Hh + j) * KW;
        const float* __restrict__ wb3 = P.Wb + (size_t)(3 * Hh + j) * KW;
        const float* __restrict__ wr0 = P.Wr + (size_t)(0 * Hh + j) * KW;
        const float* __restrict__ wr1 = P.Wr + (size_t)(1 * Hh + j) * KW;
        const float* __restrict__ wr2 = P.Wr + (size_t)(2 * Hh + j) * KW;
        const float* __restrict__ wr3 = P.Wr + (size_t)(3 * Hh + j) * KW;
        const float* __restrict__ wt0 = hasT ? P.Wt + (size_t)(0 * Hh + j) * KW : nullptr;
        const float* __restrict__ wt1 = hasT ? P.Wt + (size_t)(1 * Hh + j) * KW : nullptr;
        const float* __restrict__ wt2 = hasT ? P.Wt + (size_t)(2 * Hh + j) * KW : nullptr;
        const float* __restrict__ wt3 = hasT ? P.Wt + (size_t)(3 * Hh + j) * KW : nullptr;
        const float* __restrict__ xrow = (l == 0) ? P.x + ((size_t)lane * Tt + t) * Hh : nullptr;

        float a0 = 0.f, a1 = 0.f, a2 = 0.f, a3 = 0.f;
#pragma unroll 8
        for (int k = k0; k < k0 + 32; ++k) {
            float hbv = (l == 0) ? xrow[k] : P.hb_rd[k * 64 + lane];
            float hv  = P.h_rd[k * 64 + lane];
            float hbz = zb * hbv;
            a0 += wb0[k] * hbz + wr0[k] * hv;
            a1 += wb1[k] * hbz + wr1[k] * hv;
            a2 += wb2[k] * hbz + wr2[k] * hv;
            a3 += wb3[k] * hbz + wr3[k] * hv;
            if (hasT) {
                float htz = zo * P.ht_rd[k * 64 + lane];
                a0 += wt0[k] * htz;
                a1 += wt1[k] * htz;
                a2 += wt2[k] * htz;
                a3 += wt3[k] * htz;
            }
        }
        sred[wv][0][lane] = a0; sred[wv][1][lane] = a1;
        sred[wv][2][lane] = a2; sred[wv][3][lane] = a3;
        __syncthreads();
        if (tid < 64) {
            const int b = tid;
            float s0 = P.bias[0 * Hh + j];
            float s1 = P.bias[1 * Hh + j];
            float s2 = P.bias[2 * Hh + j];
            float s3 = P.bias[3 * Hh + j];
#pragma unroll
            for (int v = 0; v < 8; ++v) {
                s0 += sred[v][0][b]; s1 += sred[v][1][b];
                s2 += sred[v][2][b]; s3 += sred[v][3][b];
            }
            float f = 1.0f / (1.0f + expf(-s0));
            float i = 1.0f / (1.0f + expf(-s1));
            float o = 1.0f / (1.0f + expf(-s2));
            float g = tanhf(s3);
            float zb_ = (l == 0) ? 1.0f : P.zb_rd[b];
            float zo_ = P.z_rd[b];
            float c    = P.c_rd[j * 64 + b];
            float hold = P.h_rd[j * 64 + b];
            float ig   = i * g;
            float cupd = f * c + ig;
            float cnew = (zo_ != 0.0f) ? ig : ((zb_ != 0.0f) ? cupd : c);
            float hnew = (zo_ == 0.0f && zb_ == 0.0f) ? hold : (o * tanhf(cnew));
            P.c_wr[j * 64 + b] = cnew;
            P.h_wr[j * 64 + b] = hnew;
            P.out_h[((size_t)b * Tt + t) * (3 * Hh) + l * Hh + j] = hnew;
        }
    } else {
        const float* __restrict__ wbz = P.Wb + (size_t)1024 * KW;
        const float* __restrict__ wrz = P.Wr + (size_t)1024 * KW;
        const float* __restrict__ wtz = (l < 2) ? P.Wt + (size_t)1024 * KW : nullptr;
        const float* __restrict__ xrow = (l == 0) ? P.x + ((size_t)lane * Tt + t) * Hh : nullptr;
        double aB = 0.0, aR = 0.0, aT = 0.0;
#pragma unroll 4
        for (int k = k0; k < k0 + 32; ++k) {
            float hbv = (l == 0) ? xrow[k] : P.hb_rd[k * 64 + lane];
            aB += (double)wbz[k] * (double)hbv;
            aR += (double)wrz[k] * (double)P.h_rd[k * 64 + lane];
            if (l < 2) aT += (double)wtz[k] * (double)P.ht_rd[k * 64 + lane];
        }
        zred[wv][0][lane] = aB; zred[wv][1][lane] = aR; zred[wv][2][lane] = aT;
        __syncthreads();
        if (tid < 64) {
            const int b = tid;
            double sB = 0.0, sR = 0.0, sT = 0.0;
#pragma unroll
            for (int v = 0; v < 8; ++v) {
                sB += zred[v][0][b]; sR += zred[v][1][b]; sT += zred[v][2][b];
            }
            double zb_ = (l == 0) ? 1.0 : (double)P.zb_rd[b];
            double zo_ = (double)P.z_rd[b];
            double s = (double)P.bias[1024] + zb_ * sB + sR + zo_ * sT;
            float znew = (s > 0.0) ? 1.0f : 0.0f;
            P.z_wr[b] = znew;
            P.out_z[((size_t)b * Tt + t) * 3 + l] = znew;
        }
    }
}

extern "C" void kernel_launch(void* const* d_in, const int* in_sizes, int n_in,
                              void* d_out, int out_size, void* d_ws, size_t ws_size,
                              hipStream_t stream) {
    (void)in_sizes; (void)n_in; (void)out_size; (void)ws_size;

    const float* x = (const float*)d_in[0];
    // dict order: x, Wb0,Wr0,Wt0,b0, Wb1,Wr1,Wt1,b1, Wb2,Wr2,Wt2,b2
    float* wsf = (float*)d_ws;
    float* WT  = wsf;                               // 8 * 262400 floats
    float* hT  = WT + 8 * (size_t)MATF;             // [2][3][256][64]
    float* cT  = hT + 2 * 3 * Hh * Bb;              // [2][3][256][64]
    float* zS  = cT + 2 * 3 * Hh * Bb;              // [2][3][64]

    // Zero recurrent state each call (ws not re-poisoned between replays;
    // t=0 reads parity-0 state as the zero initial condition).
    size_t clearBytes = (size_t)(2 * 3 * Hh * Bb * 2 + 2 * 3 * Bb) * sizeof(float);
    hipMemsetAsync(hT, 0, clearBytes, stream);

    Ptrs8 ps;
    const int mi[8] = { 1, 2, 3, 5, 6, 7, 9, 10 };  // Wb0,Wr0,Wt0,Wb1,Wr1,Wt1,Wb2,Wr2
    for (int i = 0; i < 8; ++i) ps.p[i] = (const float*)d_in[mi[i]];
    transpose_w<<<dim3(256, 8), 256, 0, stream>>>(ps, WT);

    float* out_h = (float*)d_out;
    float* out_z = out_h + (size_t)Bb * Tt * (3 * Hh);

    PK pk;
    pk.x = x;
    for (int i = 0; i < 8; ++i) pk.W[i] = WT + (size_t)i * MATF;
    pk.bias[0] = (const float*)d_in[4];
    pk.bias[1] = (const float*)d_in[8];
    pk.bias[2] = (const float*)d_in[12];
    pk.hT = hT; pk.cT = cT; pk.zS = zS;
    pk.out_h = out_h;
    pk.out_z = out_z;

    void* args[] = { &pk };
    hipError_t e = hipLaunchCooperativeKernel((void*)persistent_kernel,
                                              dim3(256), dim3(512), args, 0, stream);
    if (e == hipSuccess) return;

    // -------- fallback: proven 1536-launch path --------
    const int wmb[3] = { 0, 3, 6 };
    const int wmr[3] = { 1, 4, 7 };
    const int wmt[3] = { 2, 5, -1 };

    auto hS = [&](int pp, int ll) { return hT + ((size_t)pp * 3 + ll) * (Hh * Bb); };
    auto cS = [&](int pp, int ll) { return cT + ((size_t)pp * 3 + ll) * (Hh * Bb); };
    auto zSl = [&](int pp, int ll) { return zS + ((size_t)pp * 3 + ll) * Bb; };

    for (int t = 0; t < Tt; ++t) {
        int p = t & 1;
        for (int l = 0; l < 3; ++l) {
            StageP P;
            P.x    = (l == 0) ? x : nullptr;
            P.Wb   = WT + (size_t)wmb[l] * MATF;
            P.Wr   = WT + (size_t)wmr[l] * MATF;
            P.Wt   = (l < 2) ? WT + (size_t)wmt[l] * MATF : nullptr;
            P.bias = (l == 0) ? (const float*)d_in[4] : (l == 1) ? (const float*)d_in[8] : (const float*)d_in[12];
            P.h_rd  = hS(p, l);
            P.ht_rd = (l < 2) ? hS(p, l + 1) : nullptr;
            P.hb_rd = (l > 0) ? hS(p ^ 1, l - 1) : nullptr;
            P.c_rd  = cS(p, l);
            P.c_wr  = cS(p ^ 1, l);
            P.z_rd  = zSl(p, l);
            P.zb_rd = (l > 0) ? zSl(p ^ 1, l - 1) : nullptr;
            P.h_wr  = hS(p ^ 1, l);
            P.z_wr  = zSl(p ^ 1, l);
            P.out_h = out_h;
            P.out_z = out_z;
            P.t     = t;
            P.layer = l;
            stage_kernel<<<257, 512, 0, stream>>>(P);
        }
    }
}

// Round 4
// 58314.661 us; speedup vs baseline: 1.5843x; 1.5843x over previous
//
#include <hip/hip_runtime.h>
#include <cmath>

// HM-LSTM forward, MI355X. Round 3:
//  - Persistent cooperative kernel (256 WGs x 512 thr), but NO cg::sync and NO
//    fences: cross-WG state (h, z) is exchanged via RELAXED AGENT-scope atomics
//    (sc1 L2-bypass, coherent at the memory-side L3), and the inter-stage
//    barrier is a hand-rolled 32-leaf+root counter tree of relaxed agent
//    atomics with s_sleep spin. L2 is never written back or invalidated, so
//    the ~3 MB/layer weight set stays L2-hot for all 1536 stages (round 2's
//    cg::sync flushed L2 every stage: 26 GB HBM traffic, 60 us/stage, 96% of
//    time in the barrier).
//  - Ordering: __syncthreads() drains vmcnt per wave (compiler-guaranteed)
//    before the thread-0 barrier arrival, so bypass stores are L3-visible
//    before the counter increment; consumers' bypass loads issue after the
//    spin exit and read L3.
//  - c and h_old for column j are PRIVATE to WG j -> kept in registers
//    (creg/hreg, l fully unrolled for static indexing). z exchanged as a
//    64-bit ballot mask (one 8B store by WG0, one 8B load per WG).
//  - Fallback to the proven 1536-launch path if coop launch is rejected.

#define Hh   256
#define Bb   64
#define Tt   512
#define GC   1025
#define KW   256
#define MATF (GC * KW)          // 262400 floats per transposed matrix

// ---------------- device-scope (L3) access helpers ----------------
__device__ __forceinline__ float g_ld(const float* p) {
    return __hip_atomic_load((const float*)p, __ATOMIC_RELAXED, __HIP_MEMORY_SCOPE_AGENT);
}
__device__ __forceinline__ void g_st(float* p, float v) {
    __hip_atomic_store(p, v, __ATOMIC_RELAXED, __HIP_MEMORY_SCOPE_AGENT);
}
__device__ __forceinline__ unsigned long long g_ld64(const unsigned long long* p) {
    return __hip_atomic_load(p, __ATOMIC_RELAXED, __HIP_MEMORY_SCOPE_AGENT);
}
__device__ __forceinline__ void g_st64(unsigned long long* p, unsigned long long v) {
    __hip_atomic_store(p, v, __ATOMIC_RELAXED, __HIP_MEMORY_SCOPE_AGENT);
}

struct Ptrs8 { const float* p[8]; };

__global__ __launch_bounds__(256) void transpose_w(Ptrs8 srcs, float* __restrict__ dst) {
    int k = blockIdx.x;                    // 0..255 (row of source = K index)
    int m = blockIdx.y;                    // 0..7   (matrix)
    const float* __restrict__ src = srcs.p[m];
    float* __restrict__ d = dst + (size_t)m * MATF;
#pragma unroll
    for (int c = 0; c < 5; ++c) {
        int col = c * 256 + threadIdx.x;
        if (col < GC) d[(size_t)col * KW + k] = src[(size_t)k * GC + col];
    }
}

// ---------------------------------------------------------------------------
// Persistent kernel
// ---------------------------------------------------------------------------
struct PK {
    const float* x;
    const float* W[8];      // transposed: Wb0,Wr0,Wt0, Wb1,Wr1,Wt1, Wb2,Wr2
    const float* bias[3];
    float* hT;              // [2][3][256*64]  (L3-exchanged)
    unsigned long long* zM; // [2][3] ballot masks (L3-exchanged)
    unsigned int* leaf;     // 32 leaves x 32 uints (128B apart)
    unsigned int* root;
    float* out_h;           // (B,T,768)
    float* out_z;           // (B,T,3)
};

__global__ __launch_bounds__(512, 2) void persistent_kernel(PK P) {
    __shared__ float  sred[8][4][64];
    __shared__ double zred[8][3][64];
    __shared__ unsigned long long smask[2];

    const int tid  = threadIdx.x;
    const int lane = tid & 63;    // batch row
    const int wv   = tid >> 6;    // 0..7, K chunk
    const int wg   = blockIdx.x;  // 0..255 = gate column j
    const int k0   = wv * 32;

    float hreg[3] = {0.f, 0.f, 0.f};   // own-column h (tid<64 only)
    float creg[3] = {0.f, 0.f, 0.f};   // own-column c (tid<64 only)
    unsigned int leafTgt = 0, rootTgt = 0;

    for (int t = 0; t < Tt; ++t) {
        const int p = t & 1;
#pragma unroll
        for (int l = 0; l < 3; ++l) {
            const float* __restrict__ h_rd  = P.hT + (size_t)(p * 3 + l) * (Hh * Bb);
            const float* __restrict__ ht_rd = (l < 2) ? P.hT + (size_t)(p * 3 + l + 1) * (Hh * Bb) : nullptr;
            const float* __restrict__ hb_rd = (l > 0) ? P.hT + (size_t)((p ^ 1) * 3 + l - 1) * (Hh * Bb) : nullptr;
            float*       __restrict__ h_wr  = P.hT + (size_t)((p ^ 1) * 3 + l) * (Hh * Bb);
            const float* __restrict__ Wb = P.W[l * 3];
            const float* __restrict__ Wr = P.W[l * 3 + 1];
            const float* __restrict__ Wt = (l < 2) ? P.W[l * 3 + 2] : nullptr;
            const float* __restrict__ bias = P.bias[l];
            const bool hasT = (l < 2);

            // ---- stage z masks into LDS (one 8B bypass load each) ----
            if (tid == 0)  smask[0] = g_ld64(&P.zM[p * 3 + l]);
            if (tid == 64) smask[1] = (l > 0) ? g_ld64(&P.zM[(p ^ 1) * 3 + (l - 1)])
                                              : ~0ull;
            __syncthreads();
            const float zo = (float)((smask[0] >> lane) & 1ull);
            const float zb = (float)((smask[1] >> lane) & 1ull);

            // ---- gate columns {j, 256+j, 512+j, 768+j} for WG j ----
            {
                const int j = wg;
                const float* __restrict__ wb0 = Wb + (size_t)(0 * Hh + j) * KW;
                const float* __restrict__ wb1 = Wb + (size_t)(1 * Hh + j) * KW;
                const float* __restrict__ wb2 = Wb + (size_t)(2 * Hh + j) * KW;
                const float* __restrict__ wb3 = Wb + (size_t)(3 * Hh + j) * KW;
                const float* __restrict__ wr0 = Wr + (size_t)(0 * Hh + j) * KW;
                const float* __restrict__ wr1 = Wr + (size_t)(1 * Hh + j) * KW;
                const float* __restrict__ wr2 = Wr + (size_t)(2 * Hh + j) * KW;
                const float* __restrict__ wr3 = Wr + (size_t)(3 * Hh + j) * KW;
                const float* __restrict__ wt0 = hasT ? Wt + (size_t)(0 * Hh + j) * KW : nullptr;
                const float* __restrict__ wt1 = hasT ? Wt + (size_t)(1 * Hh + j) * KW : nullptr;
                const float* __restrict__ wt2 = hasT ? Wt + (size_t)(2 * Hh + j) * KW : nullptr;
                const float* __restrict__ wt3 = hasT ? Wt + (size_t)(3 * Hh + j) * KW : nullptr;

                float a0 = 0.f, a1 = 0.f, a2 = 0.f, a3 = 0.f;

                if (l == 0) {
                    const float4* __restrict__ xp =
                        (const float4*)(P.x + ((size_t)lane * Tt + t) * Hh + k0);
                    float xr[32];
#pragma unroll
                    for (int q = 0; q < 8; ++q) {
                        float4 v = xp[q];
                        xr[4 * q + 0] = v.x; xr[4 * q + 1] = v.y;
                        xr[4 * q + 2] = v.z; xr[4 * q + 3] = v.w;
                    }
#pragma unroll
                    for (int kk = 0; kk < 32; ++kk) {
                        const int k = k0 + kk;
                        float hbz = xr[kk];       // z_bottom == 1 exactly
                        float hv  = g_ld(&h_rd[k * 64 + lane]);
                        a0 += wb0[k] * hbz + wr0[k] * hv;
                        a1 += wb1[k] * hbz + wr1[k] * hv;
                        a2 += wb2[k] * hbz + wr2[k] * hv;
                        a3 += wb3[k] * hbz + wr3[k] * hv;
                        float htz = zo * g_ld(&ht_rd[k * 64 + lane]);
                        a0 += wt0[k] * htz;
                        a1 += wt1[k] * htz;
                        a2 += wt2[k] * htz;
                        a3 += wt3[k] * htz;
                    }
                } else {
#pragma unroll 8
                    for (int k = k0; k < k0 + 32; ++k) {
                        float hbz = zb * g_ld(&hb_rd[k * 64 + lane]);
                        float hv  = g_ld(&h_rd[k * 64 + lane]);
                        a0 += wb0[k] * hbz + wr0[k] * hv;
                        a1 += wb1[k] * hbz + wr1[k] * hv;
                        a2 += wb2[k] * hbz + wr2[k] * hv;
                        a3 += wb3[k] * hbz + wr3[k] * hv;
                        if (hasT) {
                            float htz = zo * g_ld(&ht_rd[k * 64 + lane]);
                            a0 += wt0[k] * htz;
                            a1 += wt1[k] * htz;
                            a2 += wt2[k] * htz;
                            a3 += wt3[k] * htz;
                        }
                    }
                }
                sred[wv][0][lane] = a0; sred[wv][1][lane] = a1;
                sred[wv][2][lane] = a2; sred[wv][3][lane] = a3;
                __syncthreads();
                if (tid < 64) {
                    const int b = tid;
                    float s0 = bias[0 * Hh + j];
                    float s1 = bias[1 * Hh + j];
                    float s2 = bias[2 * Hh + j];
                    float s3 = bias[3 * Hh + j];
#pragma unroll
                    for (int v = 0; v < 8; ++v) {
                        s0 += sred[v][0][b]; s1 += sred[v][1][b];
                        s2 += sred[v][2][b]; s3 += sred[v][3][b];
                    }
                    float f = 1.0f / (1.0f + expf(-s0));
                    float i = 1.0f / (1.0f + expf(-s1));
                    float o = 1.0f / (1.0f + expf(-s2));
                    float g = tanhf(s3);
                    float zb_ = (float)((smask[1] >> b) & 1ull);
                    float zo_ = (float)((smask[0] >> b) & 1ull);
                    float c    = creg[l];
                    float hold = hreg[l];
                    float ig   = i * g;
                    float cupd = f * c + ig;
                    // z, zb in {0,1} exactly -> selects == reference arithmetic
                    float cnew = (zo_ != 0.0f) ? ig : ((zb_ != 0.0f) ? cupd : c);
                    float hnew = (zo_ == 0.0f && zb_ == 0.0f) ? hold : (o * tanhf(cnew));
                    creg[l] = cnew;
                    hreg[l] = hnew;
                    g_st(&h_wr[j * 64 + b], hnew);
                    P.out_h[((size_t)b * Tt + t) * (3 * Hh) + l * Hh + j] = hnew;
                }
            }

            // ---- z column (col 1024) in fp64, WG 0 only ----
            if (wg == 0) {
                const float* __restrict__ wbz = Wb + (size_t)1024 * KW;
                const float* __restrict__ wrz = Wr + (size_t)1024 * KW;
                const float* __restrict__ wtz = hasT ? Wt + (size_t)1024 * KW : nullptr;
                double aB = 0.0, aR = 0.0, aT = 0.0;
                if (l == 0) {
                    const float4* __restrict__ xp =
                        (const float4*)(P.x + ((size_t)lane * Tt + t) * Hh + k0);
                    float xr[32];
#pragma unroll
                    for (int q = 0; q < 8; ++q) {
                        float4 v = xp[q];
                        xr[4 * q + 0] = v.x; xr[4 * q + 1] = v.y;
                        xr[4 * q + 2] = v.z; xr[4 * q + 3] = v.w;
                    }
#pragma unroll
                    for (int kk = 0; kk < 32; ++kk) {
                        const int k = k0 + kk;
                        aB += (double)wbz[k] * (double)xr[kk];
                        aR += (double)wrz[k] * (double)g_ld(&h_rd[k * 64 + lane]);
                        aT += (double)wtz[k] * (double)g_ld(&ht_rd[k * 64 + lane]);
                    }
                } else {
#pragma unroll 4
                    for (int k = k0; k < k0 + 32; ++k) {
                        aB += (double)wbz[k] * (double)g_ld(&hb_rd[k * 64 + lane]);
                        aR += (double)wrz[k] * (double)g_ld(&h_rd[k * 64 + lane]);
                        if (hasT) aT += (double)wtz[k] * (double)g_ld(&ht_rd[k * 64 + lane]);
                    }
                }
                zred[wv][0][lane] = aB; zred[wv][1][lane] = aR; zred[wv][2][lane] = aT;
                __syncthreads();
                if (tid < 64) {
                    const int b = tid;
                    double sB = 0.0, sR = 0.0, sT = 0.0;
#pragma unroll
                    for (int v = 0; v < 8; ++v) {
                        sB += zred[v][0][b]; sR += zred[v][1][b]; sT += zred[v][2][b];
                    }
                    double zb_ = (double)((smask[1] >> b) & 1ull);
                    double zo_ = (double)((smask[0] >> b) & 1ull);
                    double s = (double)bias[1024] + zb_ * sB + sR + zo_ * sT;
                    // round(clip((s+1)/2,0,1)) with round-half-even == (s > 0)
                    float znew = (s > 0.0) ? 1.0f : 0.0f;
                    unsigned long long m = __ballot(znew != 0.0f);
                    if (b == 0) g_st64(&P.zM[(p ^ 1) * 3 + l], m);
                    P.out_z[((size_t)b * Tt + t) * 3 + l] = znew;
                }
            }

            // ---- stage barrier: 32-leaf + root tree, relaxed agent atomics.
            // __syncthreads drains each wave's vmcnt, so this WG's bypass
            // stores are L3-visible before the arrival increment.
            __syncthreads();
            leafTgt += 8;      // 256 WGs / 32 leaves
            rootTgt += 32;
            if (tid == 0) {
                unsigned int* lc = P.leaf + (size_t)(wg & 31) * 32;
                unsigned int prev = __hip_atomic_fetch_add(lc, 1u, __ATOMIC_RELAXED,
                                                           __HIP_MEMORY_SCOPE_AGENT);
                if (prev == leafTgt - 1)
                    __hip_atomic_fetch_add(P.root, 1u, __ATOMIC_RELAXED,
                                           __HIP_MEMORY_SCOPE_AGENT);
                while (__hip_atomic_load(P.root, __ATOMIC_RELAXED,
                                         __HIP_MEMORY_SCOPE_AGENT) < rootTgt)
                    __builtin_amdgcn_s_sleep(2);
            }
            __syncthreads();
        }
    }
}

// ---------------------------------------------------------------------------
// Fallback path: round-0 per-stage kernel (proven correct), used only if the
// cooperative launch is rejected by the runtime.
// ---------------------------------------------------------------------------
struct StageP {
    const float* x;
    const float* Wb;
    const float* Wr;
    const float* Wt;
    const float* bias;
    const float* h_rd;
    const float* ht_rd;
    const float* hb_rd;
    const float* c_rd;
    float*       c_wr;
    const float* z_rd;
    const float* zb_rd;
    float*       h_wr;
    float*       z_wr;
    float*       out_h;
    float*       out_z;
    int          t;
    int          layer;
};

__global__ __launch_bounds__(512) void stage_kernel(StageP P) {
    __shared__ float  sred[8][4][64];
    __shared__ double zred[8][3][64];

    const int tid  = threadIdx.x;
    const int lane = tid & 63;
    const int wv   = tid >> 6;
    const int wg   = blockIdx.x;
    const int t = P.t, l = P.layer;
    const int k0 = wv * 32;

    if (wg < 256) {
        const int j = wg;
        const float zb = (l == 0) ? 1.0f : P.zb_rd[lane];
        const float zo = P.z_rd[lane];
        const bool hasT = (l < 2);

        const float* __restrict__ wb0 = P.Wb + (size_t)(0 * Hh + j) * KW;
        const float* __restrict__ wb1 = P.Wb + (size_t)(1 * Hh + j) * KW;
        const float* __restrict__ wb2 = P.Wb + (size_t)(2 * Hh + j) * KW;
        const float* __restrict__ wb3 = P.Wb + (size_t)(3 * Hh + j) * KW;
        const float* __restrict__ wr0 = P.Wr + (size_t)(0 * Hh + j) * KW;
        const float* __restrict__ wr1 = P.Wr + (size_t)(1 * Hh + j) * KW;
        const float* __restrict__ wr2 = P.Wr + (size_t)(2 * Hh + j) * KW;
        const float* __restrict__ wr3 = P.Wr + (size_t)(3 * Hh + j) * KW;
        const float* __restrict__ wt0 = hasT ? P.Wt + (size_t)(0 * Hh + j) * KW : nullptr;
        const float* __restrict__ wt1 = hasT ? P.Wt + (size_t)(1 * Hh + j) * KW : nullptr;
        const float* __restrict__ wt2 = hasT ? P.Wt + (size_t)(2 * Hh + j) * KW : nullptr;
        const float* __restrict__ wt3 = hasT ? P.Wt + (size_t)(3 * Hh + j) * KW : nullptr;
        const float* __restrict__ xrow = (l == 0) ? P.x + ((size_t)lane * Tt + t) * Hh : nullptr;

        float a0 = 0.f, a1 = 0.f, a2 = 0.f, a3 = 0.f;
#pragma unroll 8
        for (int k = k0; k < k0 + 32; ++k) {
            float hbv = (l == 0) ? xrow[k] : P.hb_rd[k * 64 + lane];
            float hv  = P.h_rd[k * 64 + lane];
            float hbz = zb * hbv;
            a0 += wb0[k] * hbz + wr0[k] * hv;
            a1 += wb1[k] * hbz + wr1[k] * hv;
            a2 += wb2[k] * hbz + wr2[k] * hv;
            a3 += wb3[k] * hbz + wr3[k] * hv;
            if (hasT) {
                float htz = zo * P.ht_rd[k * 64 + lane];
                a0 += wt0[k] * htz;
                a1 += wt1[k] * htz;
                a2 += wt2[k] * htz;
                a3 += wt3[k] * htz;
            }
        }
        sred[wv][0][lane] = a0; sred[wv][1][lane] = a1;
        sred[wv][2][lane] = a2; sred[wv][3][lane] = a3;
        __syncthreads();
        if (tid < 64) {
            const int b = tid;
            float s0 = P.bias[0 * Hh + j];
            float s1 = P.bias[1 * Hh + j];
            float s2 = P.bias[2 * Hh + j];
            float s3 = P.bias[3 * Hh + j];
#pragma unroll
            for (int v = 0; v < 8; ++v) {
                s0 += sred[v][0][b]; s1 += sred[v][1][b];
                s2 += sred[v][2][b]; s3 += sred[v][3][b];
            }
            float f = 1.0f / (1.0f + expf(-s0));
            float i = 1.0f / (1.0f + expf(-s1));
            float o = 1.0f / (1.0f + expf(-s2));
            float g = tanhf(s3);
            float zb_ = (l == 0) ? 1.0f : P.zb_rd[b];
            float zo_ = P.z_rd[b];
            float c    = P.c_rd[j * 64 + b];
            float hold = P.h_rd[j * 64 + b];
            float ig   = i * g;
            float cupd = f * c + ig;
            float cnew = (zo_ != 0.0f) ? ig : ((zb_ != 0.0f) ? cupd : c);
            float hnew = (zo_ == 0.0f && zb_ == 0.0f) ? hold : (o * tanhf(cnew));
            P.c_wr[j * 64 + b] = cnew;
            P.h_wr[j * 64 + b] = hnew;
            P.out_h[((size_t)b * Tt + t) * (3 * Hh) + l * Hh + j] = hnew;
        }
    } else {
        const float* __restrict__ wbz = P.Wb + (size_t)1024 * KW;
        const float* __restrict__ wrz = P.Wr + (size_t)1024 * KW;
        const float* __restrict__ wtz = (l < 2) ? P.Wt + (size_t)1024 * KW : nullptr;
        const float* __restrict__ xrow = (l == 0) ? P.x + ((size_t)lane * Tt + t) * Hh : nullptr;
        double aB = 0.0, aR = 0.0, aT = 0.0;
#pragma unroll 4
        for (int k = k0; k < k0 + 32; ++k) {
            float hbv = (l == 0) ? xrow[k] : P.hb_rd[k * 64 + lane];
            aB += (double)wbz[k] * (double)hbv;
            aR += (double)wrz[k] * (double)P.h_rd[k * 64 + lane];
            if (l < 2) aT += (double)wtz[k] * (double)P.ht_rd[k * 64 + lane];
        }
        zred[wv][0][lane] = aB; zred[wv][1][lane] = aR; zred[wv][2][lane] = aT;
        __syncthreads();
        if (tid < 64) {
            const int b = tid;
            double sB = 0.0, sR = 0.0, sT = 0.0;
#pragma unroll
            for (int v = 0; v < 8; ++v) {
                sB += zred[v][0][b]; sR += zred[v][1][b]; sT += zred[v][2][b];
            }
            double zb_ = (l == 0) ? 1.0 : (double)P.zb_rd[b];
            double zo_ = (double)P.z_rd[b];
            double s = (double)P.bias[1024] + zb_ * sB + sR + zo_ * sT;
            float znew = (s > 0.0) ? 1.0f : 0.0f;
            P.z_wr[b] = znew;
            P.out_z[((size_t)b * Tt + t) * 3 + l] = znew;
        }
    }
}

extern "C" void kernel_launch(void* const* d_in, const int* in_sizes, int n_in,
                              void* d_out, int out_size, void* d_ws, size_t ws_size,
                              hipStream_t stream) {
    (void)in_sizes; (void)n_in; (void)out_size; (void)ws_size;

    const float* x = (const float*)d_in[0];
    // dict order: x, Wb0,Wr0,Wt0,b0, Wb1,Wr1,Wt1,b1, Wb2,Wr2,Wt2,b2
    float* wsf = (float*)d_ws;

    // ws layout (floats)
    const size_t OFF_HT   = 8 * (size_t)MATF;          // h slots  [2][3][256*64]
    const size_t OFF_CT   = OFF_HT + 2 * 3 * Hh * Bb;  // fallback c
    const size_t OFF_ZS   = OFF_CT + 2 * 3 * Hh * Bb;  // fallback z (float)
    const size_t OFF_ZM   = OFF_ZS + 384;              // uint64[6] ballot masks
    const size_t OFF_LEAF = OFF_ZM + 16;               // uint[32*32]
    const size_t OFF_ROOT = OFF_LEAF + 1024 + 32;      // uint, own line
    const size_t OFF_END  = OFF_ROOT + 32;

    float* WT = wsf;
    float* hT = wsf + OFF_HT;
    float* cT = wsf + OFF_CT;
    float* zS = wsf + OFF_ZS;
    unsigned long long* zM = (unsigned long long*)(wsf + OFF_ZM);
    unsigned int* leaf = (unsigned int*)(wsf + OFF_LEAF);
    unsigned int* root = (unsigned int*)(wsf + OFF_ROOT);

    // Zero all mutable state (h slots, fallback c/z, masks, barrier counters).
    hipMemsetAsync(hT, 0, (OFF_END - OFF_HT) * sizeof(float), stream);

    Ptrs8 ps;
    const int mi[8] = { 1, 2, 3, 5, 6, 7, 9, 10 };  // Wb0,Wr0,Wt0,Wb1,Wr1,Wt1,Wb2,Wr2
    for (int i = 0; i < 8; ++i) ps.p[i] = (const float*)d_in[mi[i]];
    transpose_w<<<dim3(256, 8), 256, 0, stream>>>(ps, WT);

    float* out_h = (float*)d_out;
    float* out_z = out_h + (size_t)Bb * Tt * (3 * Hh);

    PK pk;
    pk.x = x;
    for (int i = 0; i < 8; ++i) pk.W[i] = WT + (size_t)i * MATF;
    pk.bias[0] = (const float*)d_in[4];
    pk.bias[1] = (const float*)d_in[8];
    pk.bias[2] = (const float*)d_in[12];
    pk.hT = hT; pk.zM = zM; pk.leaf = leaf; pk.root = root;
    pk.out_h = out_h;
    pk.out_z = out_z;

    void* args[] = { &pk };
    hipError_t e = hipLaunchCooperativeKernel((void*)persistent_kernel,
                                              dim3(256), dim3(512), args, 0, stream);
    if (e == hipSuccess) return;

    // -------- fallback: proven 1536-launch path --------
    const int wmb[3] = { 0, 3, 6 };
    const int wmr[3] = { 1, 4, 7 };
    const int wmt[3] = { 2, 5, -1 };

    auto hS = [&](int pp, int ll) { return hT + ((size_t)pp * 3 + ll) * (Hh * Bb); };
    auto cS = [&](int pp, int ll) { return cT + ((size_t)pp * 3 + ll) * (Hh * Bb); };
    auto zSl = [&](int pp, int ll) { return zS + ((size_t)pp * 3 + ll) * Bb; };

    for (int t = 0; t < Tt; ++t) {
        int p = t & 1;
        for (int l = 0; l < 3; ++l) {
            StageP P;
            P.x    = (l == 0) ? x : nullptr;
            P.Wb   = WT + (size_t)wmb[l] * MATF;
            P.Wr   = WT + (size_t)wmr[l] * MATF;
            P.Wt   = (l < 2) ? WT + (size_t)wmt[l] * MATF : nullptr;
            P.bias = (l == 0) ? (const float*)d_in[4] : (l == 1) ? (const float*)d_in[8] : (const float*)d_in[12];
            P.h_rd  = hS(p, l);
            P.ht_rd = (l < 2) ? hS(p, l + 1) : nullptr;
            P.hb_rd = (l > 0) ? hS(p ^ 1, l - 1) : nullptr;
            P.c_rd  = cS(p, l);
            P.c_wr  = cS(p ^ 1, l);
            P.z_rd  = zSl(p, l);
            P.zb_rd = (l > 0) ? zSl(p ^ 1, l - 1) : nullptr;
            P.h_wr  = hS(p ^ 1, l);
            P.z_wr  = zSl(p ^ 1, l);
            P.out_h = out_h;
            P.out_z = out_z;
            P.t     = t;
            P.layer = l;
            stage_kernel<<<257, 512, 0, stream>>>(P);
        }
    }
}

// Round 5
// 43251.239 us; speedup vs baseline: 2.1361x; 1.3483x over previous
//
#include <hip/hip_runtime.h>
#include <cmath>

// HM-LSTM forward, MI355X. Round 4:
//  - Persistent cooperative kernel (256 WGs x 512 thr), tree barrier of
//    relaxed agent atomics (proven r3/r4). Cross-WG h exchange:
//      WRITE: agent-scope (sc1, L2-bypass) store  -> lands at coherent L3.
//      READ : NORMAL cached load from a UNIQUE per-stage slot hAll[(t+1)*3+l]
//             -> no L2 line can be stale (address never read before), and
//             each XCD's L2 amortizes the read across its 32 resident WGs.
//    (r4 lesson: agent-scope atomic LOADS bypass L2 -> 256x-redundant fabric
//     reads, 42 MB/stage, fabric-BW-bound at 1.46 TB/s.)
//  - hAll = 513*3 slots x (16384+32) floats (~101 MB in ws). 128B pad per
//    slot so no line straddles slots (prefetch safety). Slot memory order ==
//    stage order. Requires ws_size >= ~110 MB, else proven fallback path.
//  - z exchanged as 64-bit ballot masks via bypass ld/st (tiny, proven).
//  - c, h_old for column j are WG-private registers.
//  - z column in fp64 (binarization boundary must match numpy fp32 ref).

#define Hh    256
#define Bb    64
#define Tt    512
#define GC    1025
#define KW    256
#define MATF  (GC * KW)          // 262400 floats per transposed matrix
#define SLOTF (Hh * Bb + 32)     // 16416 floats: 64KB slot + 128B pad

// ---------------- L3-coherent (L2-bypass) access helpers ----------------
__device__ __forceinline__ void g_st(float* p, float v) {
    __hip_atomic_store(p, v, __ATOMIC_RELAXED, __HIP_MEMORY_SCOPE_AGENT);
}
__device__ __forceinline__ unsigned long long g_ld64(const unsigned long long* p) {
    return __hip_atomic_load(p, __ATOMIC_RELAXED, __HIP_MEMORY_SCOPE_AGENT);
}
__device__ __forceinline__ void g_st64(unsigned long long* p, unsigned long long v) {
    __hip_atomic_store(p, v, __ATOMIC_RELAXED, __HIP_MEMORY_SCOPE_AGENT);
}

struct Ptrs8 { const float* p[8]; };

__global__ __launch_bounds__(256) void transpose_w(Ptrs8 srcs, float* __restrict__ dst) {
    int k = blockIdx.x;                    // 0..255 (row of source = K index)
    int m = blockIdx.y;                    // 0..7   (matrix)
    const float* __restrict__ src = srcs.p[m];
    float* __restrict__ d = dst + (size_t)m * MATF;
#pragma unroll
    for (int c = 0; c < 5; ++c) {
        int col = c * 256 + threadIdx.x;
        if (col < GC) d[(size_t)col * KW + k] = src[(size_t)k * GC + col];
    }
}

// ---------------------------------------------------------------------------
// Persistent kernel
// ---------------------------------------------------------------------------
struct PK {
    const float* x;
    const float* W[8];      // transposed: Wb0,Wr0,Wt0, Wb1,Wr1,Wt1, Wb2,Wr2
    const float* bias[3];
    float* hAll;            // [513*3] slots of SLOTF floats (unique per stage)
    unsigned long long* zM; // [2][3] ballot masks (L3-exchanged)
    unsigned int* leaf;     // 32 leaves x 32 uints (128B apart)
    unsigned int* root;
    float* out_h;           // (B,T,768)
    float* out_z;           // (B,T,3)
};

__global__ __launch_bounds__(512, 2) void persistent_kernel(PK P) {
    __shared__ float  sred[8][4][64];
    __shared__ double zred[8][3][64];
    __shared__ unsigned long long smask[2];

    const int tid  = threadIdx.x;
    const int lane = tid & 63;    // batch row
    const int wv   = tid >> 6;    // 0..7, K chunk
    const int wg   = blockIdx.x;  // 0..255 = gate column j
    const int k0   = wv * 32;

    float hreg[3] = {0.f, 0.f, 0.f};   // own-column h (tid<64 only)
    float creg[3] = {0.f, 0.f, 0.f};   // own-column c (tid<64 only)
    unsigned int leafTgt = 0, rootTgt = 0;

    for (int t = 0; t < Tt; ++t) {
        const int p = t & 1;
#pragma unroll
        for (int l = 0; l < 3; ++l) {
            // unique-slot addressing: slot s=(tIdx*3+l); write at stage (t,l)
            // goes to tIdx=t+1; reads pull tIdx<=t+1 slots written earlier.
            const float* __restrict__ h_rd  = P.hAll + ((size_t)t * 3 + l) * SLOTF;
            const float* __restrict__ ht_rd = (l < 2) ? P.hAll + ((size_t)t * 3 + l + 1) * SLOTF : nullptr;
            const float* __restrict__ hb_rd = (l > 0) ? P.hAll + ((size_t)(t + 1) * 3 + l - 1) * SLOTF : nullptr;
            float*       __restrict__ h_wr  = P.hAll + ((size_t)(t + 1) * 3 + l) * SLOTF;
            const float* __restrict__ Wb = P.W[l * 3];
            const float* __restrict__ Wr = P.W[l * 3 + 1];
            const float* __restrict__ Wt = (l < 2) ? P.W[l * 3 + 2] : nullptr;
            const float* __restrict__ bias = P.bias[l];
            const bool hasT = (l < 2);

            // ---- stage z masks into LDS (one 8B bypass load each) ----
            if (tid == 0)  smask[0] = g_ld64(&P.zM[p * 3 + l]);
            if (tid == 64) smask[1] = (l > 0) ? g_ld64(&P.zM[(p ^ 1) * 3 + (l - 1)])
                                              : ~0ull;
            __syncthreads();
            const float zo = (float)((smask[0] >> lane) & 1ull);
            const float zb = (float)((smask[1] >> lane) & 1ull);

            // ---- gate columns {j, 256+j, 512+j, 768+j} for WG j ----
            {
                const int j = wg;
                const float* __restrict__ wb0 = Wb + (size_t)(0 * Hh + j) * KW;
                const float* __restrict__ wb1 = Wb + (size_t)(1 * Hh + j) * KW;
                const float* __restrict__ wb2 = Wb + (size_t)(2 * Hh + j) * KW;
                const float* __restrict__ wb3 = Wb + (size_t)(3 * Hh + j) * KW;
                const float* __restrict__ wr0 = Wr + (size_t)(0 * Hh + j) * KW;
                const float* __restrict__ wr1 = Wr + (size_t)(1 * Hh + j) * KW;
                const float* __restrict__ wr2 = Wr + (size_t)(2 * Hh + j) * KW;
                const float* __restrict__ wr3 = Wr + (size_t)(3 * Hh + j) * KW;
                const float* __restrict__ wt0 = hasT ? Wt + (size_t)(0 * Hh + j) * KW : nullptr;
                const float* __restrict__ wt1 = hasT ? Wt + (size_t)(1 * Hh + j) * KW : nullptr;
                const float* __restrict__ wt2 = hasT ? Wt + (size_t)(2 * Hh + j) * KW : nullptr;
                const float* __restrict__ wt3 = hasT ? Wt + (size_t)(3 * Hh + j) * KW : nullptr;

                float a0 = 0.f, a1 = 0.f, a2 = 0.f, a3 = 0.f;

                if (l == 0) {
                    const float4* __restrict__ xp =
                        (const float4*)(P.x + ((size_t)lane * Tt + t) * Hh + k0);
                    float xr[32];
#pragma unroll
                    for (int q = 0; q < 8; ++q) {
                        float4 v = xp[q];
                        xr[4 * q + 0] = v.x; xr[4 * q + 1] = v.y;
                        xr[4 * q + 2] = v.z; xr[4 * q + 3] = v.w;
                    }
#pragma unroll
                    for (int kk = 0; kk < 32; ++kk) {
                        const int k = k0 + kk;
                        float hbz = xr[kk];       // z_bottom == 1 exactly
                        float hv  = h_rd[k * 64 + lane];
                        a0 += wb0[k] * hbz + wr0[k] * hv;
                        a1 += wb1[k] * hbz + wr1[k] * hv;
                        a2 += wb2[k] * hbz + wr2[k] * hv;
                        a3 += wb3[k] * hbz + wr3[k] * hv;
                        float htz = zo * ht_rd[k * 64 + lane];
                        a0 += wt0[k] * htz;
                        a1 += wt1[k] * htz;
                        a2 += wt2[k] * htz;
                        a3 += wt3[k] * htz;
                    }
                } else {
#pragma unroll 8
                    for (int k = k0; k < k0 + 32; ++k) {
                        float hbz = zb * hb_rd[k * 64 + lane];
                        float hv  = h_rd[k * 64 + lane];
                        a0 += wb0[k] * hbz + wr0[k] * hv;
                        a1 += wb1[k] * hbz + wr1[k] * hv;
                        a2 += wb2[k] * hbz + wr2[k] * hv;
                        a3 += wb3[k] * hbz + wr3[k] * hv;
                        if (hasT) {
                            float htz = zo * ht_rd[k * 64 + lane];
                            a0 += wt0[k] * htz;
                            a1 += wt1[k] * htz;
                            a2 += wt2[k] * htz;
                            a3 += wt3[k] * htz;
                        }
                    }
                }
                sred[wv][0][lane] = a0; sred[wv][1][lane] = a1;
                sred[wv][2][lane] = a2; sred[wv][3][lane] = a3;
                __syncthreads();
                if (tid < 64) {
                    const int b = tid;
                    float s0 = bias[0 * Hh + j];
                    float s1 = bias[1 * Hh + j];
                    float s2 = bias[2 * Hh + j];
                    float s3 = bias[3 * Hh + j];
#pragma unroll
                    for (int v = 0; v < 8; ++v) {
                        s0 += sred[v][0][b]; s1 += sred[v][1][b];
                        s2 += sred[v][2][b]; s3 += sred[v][3][b];
                    }
                    float f = 1.0f / (1.0f + expf(-s0));
                    float i = 1.0f / (1.0f + expf(-s1));
                    float o = 1.0f / (1.0f + expf(-s2));
                    float g = tanhf(s3);
                    float zb_ = (float)((smask[1] >> b) & 1ull);
                    float zo_ = (float)((smask[0] >> b) & 1ull);
                    float c    = creg[l];
                    float hold = hreg[l];
                    float ig   = i * g;
                    float cupd = f * c + ig;
                    // z, zb in {0,1} exactly -> selects == reference arithmetic
                    float cnew = (zo_ != 0.0f) ? ig : ((zb_ != 0.0f) ? cupd : c);
                    float hnew = (zo_ == 0.0f && zb_ == 0.0f) ? hold : (o * tanhf(cnew));
                    creg[l] = cnew;
                    hreg[l] = hnew;
                    g_st(&h_wr[j * 64 + b], hnew);   // bypass store -> L3
                    P.out_h[((size_t)b * Tt + t) * (3 * Hh) + l * Hh + j] = hnew;
                }
            }

            // ---- z column (col 1024) in fp64, WG 0 only ----
            if (wg == 0) {
                const float* __restrict__ wbz = Wb + (size_t)1024 * KW;
                const float* __restrict__ wrz = Wr + (size_t)1024 * KW;
                const float* __restrict__ wtz = hasT ? Wt + (size_t)1024 * KW : nullptr;
                double aB = 0.0, aR = 0.0, aT = 0.0;
                if (l == 0) {
                    const float4* __restrict__ xp =
                        (const float4*)(P.x + ((size_t)lane * Tt + t) * Hh + k0);
                    float xr[32];
#pragma unroll
                    for (int q = 0; q < 8; ++q) {
                        float4 v = xp[q];
                        xr[4 * q + 0] = v.x; xr[4 * q + 1] = v.y;
                        xr[4 * q + 2] = v.z; xr[4 * q + 3] = v.w;
                    }
#pragma unroll
                    for (int kk = 0; kk < 32; ++kk) {
                        const int k = k0 + kk;
                        aB += (double)wbz[k] * (double)xr[kk];
                        aR += (double)wrz[k] * (double)h_rd[k * 64 + lane];
                        aT += (double)wtz[k] * (double)ht_rd[k * 64 + lane];
                    }
                } else {
#pragma unroll 4
                    for (int k = k0; k < k0 + 32; ++k) {
                        aB += (double)wbz[k] * (double)hb_rd[k * 64 + lane];
                        aR += (double)wrz[k] * (double)h_rd[k * 64 + lane];
                        if (hasT) aT += (double)wtz[k] * (double)ht_rd[k * 64 + lane];
                    }
                }
                zred[wv][0][lane] = aB; zred[wv][1][lane] = aR; zred[wv][2][lane] = aT;
                __syncthreads();
                if (tid < 64) {
                    const int b = tid;
                    double sB = 0.0, sR = 0.0, sT = 0.0;
#pragma unroll
                    for (int v = 0; v < 8; ++v) {
                        sB += zred[v][0][b]; sR += zred[v][1][b]; sT += zred[v][2][b];
                    }
                    double zb_ = (double)((smask[1] >> b) & 1ull);
                    double zo_ = (double)((smask[0] >> b) & 1ull);
                    double s = (double)bias[1024] + zb_ * sB + sR + zo_ * sT;
                    // round(clip((s+1)/2,0,1)) with round-half-even == (s > 0)
                    float znew = (s > 0.0) ? 1.0f : 0.0f;
                    unsigned long long m = __ballot(znew != 0.0f);
                    if (b == 0) g_st64(&P.zM[(p ^ 1) * 3 + l], m);
                    P.out_z[((size_t)b * Tt + t) * 3 + l] = znew;
                }
            }

            // ---- stage barrier: 32-leaf + root tree, relaxed agent atomics.
            // __syncthreads drains each wave's vmcnt, so this WG's bypass
            // stores are L3-visible before the arrival increment.
            __syncthreads();
            leafTgt += 8;      // 256 WGs / 32 leaves
            rootTgt += 32;
            if (tid == 0) {
                unsigned int* lc = P.leaf + (size_t)(wg & 31) * 32;
                unsigned int prev = __hip_atomic_fetch_add(lc, 1u, __ATOMIC_RELAXED,
                                                           __HIP_MEMORY_SCOPE_AGENT);
                if (prev == leafTgt - 1)
                    __hip_atomic_fetch_add(P.root, 1u, __ATOMIC_RELAXED,
                                           __HIP_MEMORY_SCOPE_AGENT);
                while (__hip_atomic_load(P.root, __ATOMIC_RELAXED,
                                         __HIP_MEMORY_SCOPE_AGENT) < rootTgt)
                    __builtin_amdgcn_s_sleep(1);
            }
            __syncthreads();
        }
    }
}

// ---------------------------------------------------------------------------
// Fallback path: round-0 per-stage kernel (proven correct), used only if the
// cooperative launch is rejected or ws is too small for hAll.
// ---------------------------------------------------------------------------
struct StageP {
    const float* x;
    const float* Wb;
    const float* Wr;
    const float* Wt;
    const float* bias;
    const float* h_rd;
    const float* ht_rd;
    const float* hb_rd;
    const float* c_rd;
    float*       c_wr;
    const float* z_rd;
    const float* zb_rd;
    float*       h_wr;
    float*       z_wr;
    float*       out_h;
    float*       out_z;
    int          t;
    int          layer;
};

__global__ __launch_bounds__(512) void stage_kernel(StageP P) {
    __shared__ float  sred[8][4][64];
    __shared__ double zred[8][3][64];

    const int tid  = threadIdx.x;
    const int lane = tid & 63;
    const int wv   = tid >> 6;
    const int wg   = blockIdx.x;
    const int t = P.t, l = P.layer;
    const int k0 = wv * 32;

    if (wg < 256) {
        const int j = wg;
        const float zb = (l == 0) ? 1.0f : P.zb_rd[lane];
        const float zo = P.z_rd[lane];
        const bool hasT = (l < 2);

        const float* __restrict__ wb0 = P.Wb + (size_t)(0 * Hh + j) * KW;
        const float* __restrict__ wb1 = P.Wb + (size_t)(1 * Hh + j) * KW;
        const float* __restrict__ wb2 = P.Wb + (size_t)(2 * Hh + j) * KW;
        const float* __restrict__ wb3 = P.Wb + (size_t)(3 * Hh + j) * KW;
        const float* __restrict__ wr0 = P.Wr + (size_t)(0 * Hh + j) * KW;
        const float* __restrict__ wr1 = P.Wr + (size_t)(1 * Hh + j) * KW;
        const float* __restrict__ wr2 = P.Wr + (size_t)(2 * Hh + j) * KW;
        const float* __restrict__ wr3 = P.Wr + (size_t)(3 * Hh + j) * KW;
        const float* __restrict__ wt0 = hasT ? P.Wt + (size_t)(0 * Hh + j) * KW : nullptr;
        const float* __restrict__ wt1 = hasT ? P.Wt + (size_t)(1 * Hh + j) * KW : nullptr;
        const float* __restrict__ wt2 = hasT ? P.Wt + (size_t)(2 * Hh + j) * KW : nullptr;
        const float* __restrict__ wt3 = hasT ? P.Wt + (size_t)(3 * Hh + j) * KW : nullptr;
        const float* __restrict__ xrow = (l == 0) ? P.x + ((size_t)lane * Tt + t) * Hh : nullptr;

        float a0 = 0.f, a1 = 0.f, a2 = 0.f, a3 = 0.f;
#pragma unroll 8
        for (int k = k0; k < k0 + 32; ++k) {
            float hbv = (l == 0) ? xrow[k] : P.hb_rd[k * 64 + lane];
            float hv  = P.h_rd[k * 64 + lane];
            float hbz = zb * hbv;
            a0 += wb0[k] * hbz + wr0[k] * hv;
            a1 += wb1[k] * hbz + wr1[k] * hv;
            a2 += wb2[k] * hbz + wr2[k] * hv;
            a3 += wb3[k] * hbz + wr3[k] * hv;
            if (hasT) {
                float htz = zo * P.ht_rd[k * 64 + lane];
                a0 += wt0[k] * htz;
                a1 += wt1[k] * htz;
                a2 += wt2[k] * htz;
                a3 += wt3[k] * htz;
            }
        }
        sred[wv][0][lane] = a0; sred[wv][1][lane] = a1;
        sred[wv][2][lane] = a2; sred[wv][3][lane] = a3;
        __syncthreads();
        if (tid < 64) {
            const int b = tid;
            float s0 = P.bias[0 * Hh + j];
            float s1 = P.bias[1 * Hh + j];
            float s2 = P.bias[2 * Hh + j];
            float s3 = P.bias[3 * Hh + j];
#pragma unroll
            for (int v = 0; v < 8; ++v) {
                s0 += sred[v][0][b]; s1 += sred[v][1][b];
                s2 += sred[v][2][b]; s3 += sred[v][3][b];
            }
            float f = 1.0f / (1.0f + expf(-s0));
            float i = 1.0f / (1.0f + expf(-s1));
            float o = 1.0f / (1.0f + expf(-s2));
            float g = tanhf(s3);
            float zb_ = (l == 0) ? 1.0f : P.zb_rd[b];
            float zo_ = P.z_rd[b];
            float c    = P.c_rd[j * 64 + b];
            float hold = P.h_rd[j * 64 + b];
            float ig   = i * g;
            float cupd = f * c + ig;
            float cnew = (zo_ != 0.0f) ? ig : ((zb_ != 0.0f) ? cupd : c);
            float hnew = (zo_ == 0.0f && zb_ == 0.0f) ? hold : (o * tanhf(cnew));
            P.c_wr[j * 64 + b] = cnew;
            P.h_wr[j * 64 + b] = hnew;
            P.out_h[((size_t)b * Tt + t) * (3 * Hh) + l * Hh + j] = hnew;
        }
    } else {
        const float* __restrict__ wbz = P.Wb + (size_t)1024 * KW;
        const float* __restrict__ wrz = P.Wr + (size_t)1024 * KW;
        const float* __restrict__ wtz = (l < 2) ? P.Wt + (size_t)1024 * KW : nullptr;
        const float* __restrict__ xrow = (l == 0) ? P.x + ((size_t)lane * Tt + t) * Hh : nullptr;
        double aB = 0.0, aR = 0.0, aT = 0.0;
#pragma unroll 4
        for (int k = k0; k < k0 + 32; ++k) {
            float hbv = (l == 0) ? xrow[k] : P.hb_rd[k * 64 + lane];
            aB += (double)wbz[k] * (double)hbv;
            aR += (double)wrz[k] * (double)P.h_rd[k * 64 + lane];
            if (l < 2) aT += (double)wtz[k] * (double)P.ht_rd[k * 64 + lane];
        }
        zred[wv][0][lane] = aB; zred[wv][1][lane] = aR; zred[wv][2][lane] = aT;
        __syncthreads();
        if (tid < 64) {
            const int b = tid;
            double sB = 0.0, sR = 0.0, sT = 0.0;
#pragma unroll
            for (int v = 0; v < 8; ++v) {
                sB += zred[v][0][b]; sR += zred[v][1][b]; sT += zred[v][2][b];
            }
            double zb_ = (l == 0) ? 1.0 : (double)P.zb_rd[b];
            double zo_ = (double)P.z_rd[b];
            double s = (double)P.bias[1024] + zb_ * sB + sR + zo_ * sT;
            float znew = (s > 0.0) ? 1.0f : 0.0f;
            P.z_wr[b] = znew;
            P.out_z[((size_t)b * Tt + t) * 3 + l] = znew;
        }
    }
}

extern "C" void kernel_launch(void* const* d_in, const int* in_sizes, int n_in,
                              void* d_out, int out_size, void* d_ws, size_t ws_size,
                              hipStream_t stream) {
    (void)in_sizes; (void)n_in; (void)out_size;

    const float* x = (const float*)d_in[0];
    // dict order: x, Wb0,Wr0,Wt0,b0, Wb1,Wr1,Wt1,b1, Wb2,Wr2,Wt2,b2
    float* wsf = (float*)d_ws;

    // ws layout (floats)
    const size_t OFF_CT   = 8 * (size_t)MATF;          // fallback c [2][3][16384]
    const size_t OFF_ZS   = OFF_CT + 2 * 3 * Hh * Bb;  // fallback z (float[384])
    const size_t OFF_ZM   = OFF_ZS + 384;              // uint64[6] ballot masks
    const size_t OFF_LEAF = OFF_ZM + 32;               // uint[32*32]
    const size_t OFF_ROOT = OFF_LEAF + 1024;           // uint, own region
    const size_t OFF_HALL = OFF_ROOT + 32;             // 513*3 slots x SLOTF
    const size_t OFF_END  = OFF_HALL + (size_t)513 * 3 * SLOTF;

    float* WT = wsf;
    float* cT = wsf + OFF_CT;
    float* zS = wsf + OFF_ZS;
    unsigned long long* zM = (unsigned long long*)(wsf + OFF_ZM);
    unsigned int* leaf = (unsigned int*)(wsf + OFF_LEAF);
    unsigned int* root = (unsigned int*)(wsf + OFF_ROOT);
    float* hAll = wsf + OFF_HALL;

    const bool canCoop = ws_size >= OFF_END * sizeof(float);

    // Zero mutable state: fallback c/z + masks + barrier counters, and the
    // first 6 h slots (t=0 reads slots 0..2 as the zero initial condition;
    // fallback uses the same region as its [2][3] ping-pong).
    hipMemsetAsync(cT, 0, (OFF_HALL - OFF_CT) * sizeof(float), stream);
    size_t hZero = canCoop ? (size_t)6 * SLOTF : (size_t)2 * 3 * Hh * Bb;
    hipMemsetAsync(hAll, 0, hZero * sizeof(float), stream);

    Ptrs8 ps;
    const int mi[8] = { 1, 2, 3, 5, 6, 7, 9, 10 };  // Wb0,Wr0,Wt0,Wb1,Wr1,Wt1,Wb2,Wr2
    for (int i = 0; i < 8; ++i) ps.p[i] = (const float*)d_in[mi[i]];
    transpose_w<<<dim3(256, 8), 256, 0, stream>>>(ps, WT);

    float* out_h = (float*)d_out;
    float* out_z = out_h + (size_t)Bb * Tt * (3 * Hh);

    if (canCoop) {
        PK pk;
        pk.x = x;
        for (int i = 0; i < 8; ++i) pk.W[i] = WT + (size_t)i * MATF;
        pk.bias[0] = (const float*)d_in[4];
        pk.bias[1] = (const float*)d_in[8];
        pk.bias[2] = (const float*)d_in[12];
        pk.hAll = hAll; pk.zM = zM; pk.leaf = leaf; pk.root = root;
        pk.out_h = out_h;
        pk.out_z = out_z;
        void* args[] = { &pk };
        hipError_t e = hipLaunchCooperativeKernel((void*)persistent_kernel,
                                                  dim3(256), dim3(512), args, 0, stream);
        if (e == hipSuccess) return;
    }

    // -------- fallback: proven 1536-launch path --------
    float* hT = hAll;   // [2][3][16384] ping-pong (zeroed above)
    const int wmb[3] = { 0, 3, 6 };
    const int wmr[3] = { 1, 4, 7 };
    const int wmt[3] = { 2, 5, -1 };

    auto hS = [&](int pp, int ll) { return hT + ((size_t)pp * 3 + ll) * (Hh * Bb); };
    auto cS = [&](int pp, int ll) { return cT + ((size_t)pp * 3 + ll) * (Hh * Bb); };
    auto zSl = [&](int pp, int ll) { return zS + ((size_t)pp * 3 + ll) * Bb; };

    for (int t = 0; t < Tt; ++t) {
        int p = t & 1;
        for (int l = 0; l < 3; ++l) {
            StageP P;
            P.x    = (l == 0) ? x : nullptr;
            P.Wb   = WT + (size_t)wmb[l] * MATF;
            P.Wr   = WT + (size_t)wmr[l] * MATF;
            P.Wt   = (l < 2) ? WT + (size_t)wmt[l] * MATF : nullptr;
            P.bias = (l == 0) ? (const float*)d_in[4] : (l == 1) ? (const float*)d_in[8] : (const float*)d_in[12];
            P.h_rd  = hS(p, l);
            P.ht_rd = (l < 2) ? hS(p, l + 1) : nullptr;
            P.hb_rd = (l > 0) ? hS(p ^ 1, l - 1) : nullptr;
            P.c_rd  = cS(p, l);
            P.c_wr  = cS(p ^ 1, l);
            P.z_rd  = zSl(p, l);
            P.zb_rd = (l > 0) ? zSl(p ^ 1, l - 1) : nullptr;
            P.h_wr  = hS(p ^ 1, l);
            P.z_wr  = zSl(p ^ 1, l);
            P.out_h = out_h;
            P.out_z = out_z;
            P.t     = t;
            P.layer = l;
            stage_kernel<<<257, 512, 0, stream>>>(P);
        }
    }
}

// Round 8
// 42850.681 us; speedup vs baseline: 2.1561x; 1.0093x over previous
//
#include <hip/hip_runtime.h>
#include <cmath>

// HM-LSTM forward, MI355X. Round 7 (defensive rebuild):
//  - Skeleton = bench-r5 PROVEN kernel (43ms, passed): grid 256x512, z column
//    merged into WG 0, z masks staged tid0/tid64 -> LDS, h exchanged via sc1
//    agent stores to unique per-stage hAll slots + normal cached reads,
//    weights transposed [col][k] and L2-hot, c/h_old in registers.
//  - Kept from r6 (no sync novelty): no scattered per-stage d_out writes;
//    z history in padded zA entries (g_st64/g_ld64, proven primitives);
//    parallel epilogue expands hAll/zA -> d_out (coalesced, LDS transpose).
//  - Barrier: 32 striped groups x 8 WGs. Arrival: group-line fetch_add;
//    last arriver adds root; ONLY 32 leaders poll root; members poll their
//    group release line (8 pollers/line). All ops __hip_atomic relaxed AGENT.
//    EVERY spin has a ~0.5s watchdog + sticky 'broken' flag: on trigger the
//    WG free-runs (fast wrong answer with absmax signal, never a timeout,
//    never a wedged pod). Healthy runs never trigger it.
//  - Fallback to proven 1536-launch path if coop launch is rejected.

#define Hh    256
#define Bb    64
#define Tt    512
#define GC    1025
#define KW    256
#define MATF  (GC * KW)          // 262400 floats per transposed matrix
#define SLOTF (Hh * Bb + 32)     // 16416 floats: 64KB slot + 128B pad
#define ZSTR  32                 // uint64 stride per z entry (256B padded)
#define WDOG  2000000            // spin watchdog iterations (~0.5s)

// ---------------- agent-scope (sc1, L3) helpers — proven r3..r5 ----------------
__device__ __forceinline__ void g_st(float* p, float v) {
    __hip_atomic_store(p, v, __ATOMIC_RELAXED, __HIP_MEMORY_SCOPE_AGENT);
}
__device__ __forceinline__ unsigned long long g_ld64(const unsigned long long* p) {
    return __hip_atomic_load(p, __ATOMIC_RELAXED, __HIP_MEMORY_SCOPE_AGENT);
}
__device__ __forceinline__ void g_st64(unsigned long long* p, unsigned long long v) {
    __hip_atomic_store(p, v, __ATOMIC_RELAXED, __HIP_MEMORY_SCOPE_AGENT);
}
__device__ __forceinline__ unsigned int a_add(unsigned int* p, unsigned int v) {
    return __hip_atomic_fetch_add(p, v, __ATOMIC_RELAXED, __HIP_MEMORY_SCOPE_AGENT);
}
__device__ __forceinline__ unsigned int a_ld(const unsigned int* p) {
    return __hip_atomic_load(p, __ATOMIC_RELAXED, __HIP_MEMORY_SCOPE_AGENT);
}
// bounded spin: true = target reached, false = watchdog fired
__device__ __forceinline__ bool spin_ge(unsigned int* p, unsigned int tgt) {
    for (int i = 0; i < WDOG; ++i) {
        if (a_ld(p) >= tgt) return true;
        __builtin_amdgcn_s_sleep(1);
    }
    return false;
}

struct Ptrs8 { const float* p[8]; };

__global__ __launch_bounds__(256) void transpose_w(Ptrs8 srcs, float* __restrict__ dst) {
    int k = blockIdx.x;                    // 0..255 (row of source = K index)
    int m = blockIdx.y;                    // 0..7   (matrix)
    const float* __restrict__ src = srcs.p[m];
    float* __restrict__ d = dst + (size_t)m * MATF;
#pragma unroll
    for (int c = 0; c < 5; ++c) {
        int col = c * 256 + threadIdx.x;
        if (col < GC) d[(size_t)col * KW + k] = src[(size_t)k * GC + col];
    }
}

// ---------------------------------------------------------------------------
// Persistent kernel
// ---------------------------------------------------------------------------
struct PK {
    const float* x;
    const float* W[8];      // transposed: Wb0,Wr0,Wt0, Wb1,Wr1,Wt1, Wb2,Wr2
    const float* bias[3];
    float* hAll;            // [513*3] slots of SLOTF floats (unique per stage)
    unsigned long long* zA; // [513*3] masks, 256B apart (unique per stage)
    unsigned int* bar;      // [0]=root, [32+g*32]=grpCnt, [1056+g*32]=grpRel
    float* out_h;           // (B,T,768)
    float* out_z;           // (B,T,3)
};

__global__ __launch_bounds__(512, 2) void persistent_kernel(PK P) {
    __shared__ float  sred[8][4][64];
    __shared__ double zred[8][3][64];
    __shared__ unsigned long long smask[2];
    __shared__ float  tlds[64][65];      // epilogue transpose tile (+1 pad)

    const int tid  = threadIdx.x;
    const int lane = tid & 63;    // batch row
    const int wv   = tid >> 6;    // 0..7, K chunk
    const int wg   = blockIdx.x;  // 0..255 = gate column j; WG 0 also does z
    const int k0   = wv * 32;

    const int g = wg & 31;        // striped groups: 32 groups x 8 WGs
    unsigned int* grpCnt = &P.bar[32 + g * 32];
    unsigned int* grpRel = &P.bar[1056 + g * 32];
    unsigned int stage = 0;
    bool broken = false;

    float hreg[3] = {0.f, 0.f, 0.f};   // own-column h (tid<64 only)
    float creg[3] = {0.f, 0.f, 0.f};   // own-column c

    for (int t = 0; t < Tt; ++t) {
#pragma unroll
        for (int l = 0; l < 3; ++l) {
            // slot s = (tIdx*3+l): h_l(tIdx-1). Stage (t,l) writes tIdx=t+1.
            const float* __restrict__ h_rd  = P.hAll + ((size_t)t * 3 + l) * SLOTF;
            const float* __restrict__ ht_rd = (l < 2) ? P.hAll + ((size_t)t * 3 + l + 1) * SLOTF : nullptr;
            const float* __restrict__ hb_rd = (l > 0) ? P.hAll + ((size_t)(t + 1) * 3 + l - 1) * SLOTF : nullptr;
            float*       __restrict__ h_wr  = P.hAll + ((size_t)(t + 1) * 3 + l) * SLOTF;
            const float* __restrict__ Wb = P.W[l * 3];
            const float* __restrict__ Wr = P.W[l * 3 + 1];
            const float* __restrict__ Wt = (l < 2) ? P.W[l * 3 + 2] : nullptr;
            const float* __restrict__ bias = P.bias[l];
            const bool hasT = (l < 2);

            // ---- stage z masks into LDS (one 8B sc1 load each — proven) ----
            if (tid == 0)  smask[0] = g_ld64(&P.zA[(size_t)(t * 3 + l) * ZSTR]);
            if (tid == 64) smask[1] = (l > 0) ? g_ld64(&P.zA[(size_t)((t + 1) * 3 + l - 1) * ZSTR])
                                              : ~0ull;
            __syncthreads();
            const float zo = (float)((smask[0] >> lane) & 1ull);
            const float zb = (float)((smask[1] >> lane) & 1ull);

            // ---- gate columns {j, 256+j, 512+j, 768+j} for WG j ----
            {
                const int j = wg;
                const float* __restrict__ wb0 = Wb + (size_t)(0 * Hh + j) * KW;
                const float* __restrict__ wb1 = Wb + (size_t)(1 * Hh + j) * KW;
                const float* __restrict__ wb2 = Wb + (size_t)(2 * Hh + j) * KW;
                const float* __restrict__ wb3 = Wb + (size_t)(3 * Hh + j) * KW;
                const float* __restrict__ wr0 = Wr + (size_t)(0 * Hh + j) * KW;
                const float* __restrict__ wr1 = Wr + (size_t)(1 * Hh + j) * KW;
                const float* __restrict__ wr2 = Wr + (size_t)(2 * Hh + j) * KW;
                const float* __restrict__ wr3 = Wr + (size_t)(3 * Hh + j) * KW;
                const float* __restrict__ wt0 = hasT ? Wt + (size_t)(0 * Hh + j) * KW : nullptr;
                const float* __restrict__ wt1 = hasT ? Wt + (size_t)(1 * Hh + j) * KW : nullptr;
                const float* __restrict__ wt2 = hasT ? Wt + (size_t)(2 * Hh + j) * KW : nullptr;
                const float* __restrict__ wt3 = hasT ? Wt + (size_t)(3 * Hh + j) * KW : nullptr;

                float a0 = 0.f, a1 = 0.f, a2 = 0.f, a3 = 0.f;

                if (l == 0) {
                    const float4* __restrict__ xp =
                        (const float4*)(P.x + ((size_t)lane * Tt + t) * Hh + k0);
                    float xr[32];
#pragma unroll
                    for (int q = 0; q < 8; ++q) {
                        float4 v = xp[q];
                        xr[4 * q + 0] = v.x; xr[4 * q + 1] = v.y;
                        xr[4 * q + 2] = v.z; xr[4 * q + 3] = v.w;
                    }
#pragma unroll
                    for (int kk = 0; kk < 32; ++kk) {
                        const int k = k0 + kk;
                        float hbz = xr[kk];       // z_bottom == 1 exactly
                        float hv  = h_rd[k * 64 + lane];
                        a0 += wb0[k] * hbz + wr0[k] * hv;
                        a1 += wb1[k] * hbz + wr1[k] * hv;
                        a2 += wb2[k] * hbz + wr2[k] * hv;
                        a3 += wb3[k] * hbz + wr3[k] * hv;
                        float htz = zo * ht_rd[k * 64 + lane];
                        a0 += wt0[k] * htz;
                        a1 += wt1[k] * htz;
                        a2 += wt2[k] * htz;
                        a3 += wt3[k] * htz;
                    }
                } else {
#pragma unroll 8
                    for (int k = k0; k < k0 + 32; ++k) {
                        float hbz = zb * hb_rd[k * 64 + lane];
                        float hv  = h_rd[k * 64 + lane];
                        a0 += wb0[k] * hbz + wr0[k] * hv;
                        a1 += wb1[k] * hbz + wr1[k] * hv;
                        a2 += wb2[k] * hbz + wr2[k] * hv;
                        a3 += wb3[k] * hbz + wr3[k] * hv;
                        if (hasT) {
                            float htz = zo * ht_rd[k * 64 + lane];
                            a0 += wt0[k] * htz;
                            a1 += wt1[k] * htz;
                            a2 += wt2[k] * htz;
                            a3 += wt3[k] * htz;
                        }
                    }
                }
                sred[wv][0][lane] = a0; sred[wv][1][lane] = a1;
                sred[wv][2][lane] = a2; sred[wv][3][lane] = a3;
                __syncthreads();
                if (tid < 64) {
                    const int b = tid;   // == lane
                    float s0 = bias[0 * Hh + j];
                    float s1 = bias[1 * Hh + j];
                    float s2 = bias[2 * Hh + j];
                    float s3 = bias[3 * Hh + j];
#pragma unroll
                    for (int v = 0; v < 8; ++v) {
                        s0 += sred[v][0][b]; s1 += sred[v][1][b];
                        s2 += sred[v][2][b]; s3 += sred[v][3][b];
                    }
                    float f = 1.0f / (1.0f + expf(-s0));
                    float i = 1.0f / (1.0f + expf(-s1));
                    float o = 1.0f / (1.0f + expf(-s2));
                    float g2 = tanhf(s3);
                    float c    = creg[l];
                    float hold = hreg[l];
                    float ig   = i * g2;
                    float cupd = f * c + ig;
                    // z, zb in {0,1} exactly -> selects == reference arithmetic
                    float cnew = (zo != 0.0f) ? ig : ((zb != 0.0f) ? cupd : c);
                    float hnew = (zo == 0.0f && zb == 0.0f) ? hold : (o * tanhf(cnew));
                    creg[l] = cnew;
                    hreg[l] = hnew;
                    g_st(&h_wr[wg * 64 + b], hnew);   // sc1 store -> L3
                }
            }

            // ---- z column (col 1024) in fp64, WG 0 only (proven r5 shape) ----
            if (wg == 0) {
                const float* __restrict__ wbz = Wb + (size_t)1024 * KW;
                const float* __restrict__ wrz = Wr + (size_t)1024 * KW;
                const float* __restrict__ wtz = hasT ? Wt + (size_t)1024 * KW : nullptr;
                double aB = 0.0, aR = 0.0, aT = 0.0;
                if (l == 0) {
                    const float4* __restrict__ xp =
                        (const float4*)(P.x + ((size_t)lane * Tt + t) * Hh + k0);
                    float xr[32];
#pragma unroll
                    for (int q = 0; q < 8; ++q) {
                        float4 v = xp[q];
                        xr[4 * q + 0] = v.x; xr[4 * q + 1] = v.y;
                        xr[4 * q + 2] = v.z; xr[4 * q + 3] = v.w;
                    }
#pragma unroll
                    for (int kk = 0; kk < 32; ++kk) {
                        const int k = k0 + kk;
                        aB += (double)wbz[k] * (double)xr[kk];
                        aR += (double)wrz[k] * (double)h_rd[k * 64 + lane];
                        aT += (double)wtz[k] * (double)ht_rd[k * 64 + lane];
                    }
                } else {
#pragma unroll 4
                    for (int k = k0; k < k0 + 32; ++k) {
                        aB += (double)wbz[k] * (double)hb_rd[k * 64 + lane];
                        aR += (double)wrz[k] * (double)h_rd[k * 64 + lane];
                        if (hasT) aT += (double)wtz[k] * (double)ht_rd[k * 64 + lane];
                    }
                }
                zred[wv][0][lane] = aB; zred[wv][1][lane] = aR; zred[wv][2][lane] = aT;
                __syncthreads();
                if (tid < 64) {
                    const int b = tid;
                    double sB = 0.0, sR = 0.0, sT = 0.0;
#pragma unroll
                    for (int v = 0; v < 8; ++v) {
                        sB += zred[v][0][b]; sR += zred[v][1][b]; sT += zred[v][2][b];
                    }
                    double s = (double)bias[1024] + (double)zb * sB + sR + (double)zo * sT;
                    // round(clip((s+1)/2,0,1)) with round-half-even == (s > 0)
                    float znew = (s > 0.0) ? 1.0f : 0.0f;
                    unsigned long long m = __ballot(znew != 0.0f);
                    if (b == 0) g_st64(&P.zA[(size_t)((t + 1) * 3 + l) * ZSTR], m);
                }
            }

            // ---- group barrier (watchdog-protected) ----
            // __syncthreads drains every wave's vmcnt -> sc1 stores L3-visible
            // before arrival.
            __syncthreads();
            if (tid == 0) {
                unsigned int prev = a_add(grpCnt, 1u);
                if (prev == stage * 8u + 7u) {
                    a_add(&P.bar[0], 1u);                       // root arrival
                    if (!broken) broken = !spin_ge(&P.bar[0], (stage + 1u) * 32u);
                    a_add(grpRel, 1u);                          // group release
                } else {
                    if (!broken) broken = !spin_ge(grpRel, stage + 1u);
                }
            }
            __syncthreads();
            ++stage;
        }
    }

    // ---- epilogue: expand hAll/zA into d_out (coalesced; slots are
    //      write-once-then-read and all stores drained at last barrier). ----
    {
#pragma unroll 1
        for (int tt = 0; tt < 2; ++tt) {
            const int t = wg * 2 + tt;
#pragma unroll 1
            for (int l = 0; l < 3; ++l) {
                const float* __restrict__ slot = P.hAll + ((size_t)(t + 1) * 3 + l) * SLOTF;
#pragma unroll 1
                for (int jc = 0; jc < 4; ++jc) {
                    __syncthreads();
                    {   // load 64j x 64b chunk -> LDS (coalesced float4 x2)
                        const int f = tid * 8;
                        const int j = f >> 6;
                        const int b = f & 63;
                        const float* src = slot + (size_t)(jc * 64 + j) * 64 + b;
                        float4 v0 = *(const float4*)(src);
                        float4 v1 = *(const float4*)(src + 4);
                        float* d = &tlds[j][b];
                        d[0] = v0.x; d[1] = v0.y; d[2] = v0.z; d[3] = v0.w;
                        d[4] = v1.x; d[5] = v1.y; d[6] = v1.z; d[7] = v1.w;
                    }
                    __syncthreads();
                    // write: wave wv covers b = wv + it*8; lanes j-contiguous
#pragma unroll
                    for (int it = 0; it < 8; ++it) {
                        const int b = wv + it * 8;
                        P.out_h[((size_t)b * Tt + t) * (3 * Hh) + l * 256 + jc * 64 + lane]
                            = tlds[lane][b];
                    }
                }
            }
        }
        if (wg == 0) {
            // out_z expansion (coalesced writes; unique-entry sc1 reads)
            for (int f = tid; f < Bb * Tt * 3; f += 512) {
                const int b  = f / (Tt * 3);
                const int r  = f % (Tt * 3);
                const int t2 = r / 3;
                const int l2 = r % 3;
                const unsigned long long m = g_ld64(&P.zA[(size_t)((t2 + 1) * 3 + l2) * ZSTR]);
                P.out_z[f] = (float)((m >> b) & 1ull);
            }
        }
    }
}

// ---------------------------------------------------------------------------
// Fallback path: round-0 per-stage kernel (proven correct).
// ---------------------------------------------------------------------------
struct StageP {
    const float* x;
    const float* Wb;
    const float* Wr;
    const float* Wt;
    const float* bias;
    const float* h_rd;
    const float* ht_rd;
    const float* hb_rd;
    const float* c_rd;
    float*       c_wr;
    const float* z_rd;
    const float* zb_rd;
    float*       h_wr;
    float*       z_wr;
    float*       out_h;
    float*       out_z;
    int          t;
    int          layer;
};

__global__ __launch_bounds__(512) void stage_kernel(StageP P) {
    __shared__ float  sred[8][4][64];
    __shared__ double zred[8][3][64];

    const int tid  = threadIdx.x;
    const int lane = tid & 63;
    const int wv   = tid >> 6;
    const int wg   = blockIdx.x;
    const int t = P.t, l = P.layer;
    const int k0 = wv * 32;

    if (wg < 256) {
        const int j = wg;
        const float zb = (l == 0) ? 1.0f : P.zb_rd[lane];
        const float zo = P.z_rd[lane];
        const bool hasT = (l < 2);

        const float* __restrict__ wb0 = P.Wb + (size_t)(0 * Hh + j) * KW;
        const float* __restrict__ wb1 = P.Wb + (size_t)(1 * Hh + j) * KW;
        const float* __restrict__ wb2 = P.Wb + (size_t)(2 * Hh + j) * KW;
        const float* __restrict__ wb3 = P.Wb + (size_t)(3 * Hh + j) * KW;
        const float* __restrict__ wr0 = P.Wr + (size_t)(0 * Hh + j) * KW;
        const float* __restrict__ wr1 = P.Wr + (size_t)(1 * Hh + j) * KW;
        const float* __restrict__ wr2 = P.Wr + (size_t)(2 * Hh + j) * KW;
        const float* __restrict__ wr3 = P.Wr + (size_t)(3 * Hh + j) * KW;
        const float* __restrict__ wt0 = hasT ? P.Wt + (size_t)(0 * Hh + j) * KW : nullptr;
        const float* __restrict__ wt1 = hasT ? P.Wt + (size_t)(1 * Hh + j) * KW : nullptr;
        const float* __restrict__ wt2 = hasT ? P.Wt + (size_t)(2 * Hh + j) * KW : nullptr;
        const float* __restrict__ wt3 = hasT ? P.Wt + (size_t)(3 * Hh + j) * KW : nullptr;
        const float* __restrict__ xrow = (l == 0) ? P.x + ((size_t)lane * Tt + t) * Hh : nullptr;

        float a0 = 0.f, a1 = 0.f, a2 = 0.f, a3 = 0.f;
#pragma unroll 8
        for (int k = k0; k < k0 + 32; ++k) {
            float hbv = (l == 0) ? xrow[k] : P.hb_rd[k * 64 + lane];
            float hv  = P.h_rd[k * 64 + lane];
            float hbz = zb * hbv;
            a0 += wb0[k] * hbz + wr0[k] * hv;
            a1 += wb1[k] * hbz + wr1[k] * hv;
            a2 += wb2[k] * hbz + wr2[k] * hv;
            a3 += wb3[k] * hbz + wr3[k] * hv;
            if (hasT) {
                float htz = zo * P.ht_rd[k * 64 + lane];
                a0 += wt0[k] * htz;
                a1 += wt1[k] * htz;
                a2 += wt2[k] * htz;
                a3 += wt3[k] * htz;
            }
        }
        sred[wv][0][lane] = a0; sred[wv][1][lane] = a1;
        sred[wv][2][lane] = a2; sred[wv][3][lane] = a3;
        __syncthreads();
        if (tid < 64) {
            const int b = tid;
            float s0 = P.bias[0 * Hh + j];
            float s1 = P.bias[1 * Hh + j];
            float s2 = P.bias[2 * Hh + j];
            float s3 = P.bias[3 * Hh + j];
#pragma unroll
            for (int v = 0; v < 8; ++v) {
                s0 += sred[v][0][b]; s1 += sred[v][1][b];
                s2 += sred[v][2][b]; s3 += sred[v][3][b];
            }
            float f = 1.0f / (1.0f + expf(-s0));
            float i = 1.0f / (1.0f + expf(-s1));
            float o = 1.0f / (1.0f + expf(-s2));
            float g = tanhf(s3);
            float zb_ = (l == 0) ? 1.0f : P.zb_rd[b];
            float zo_ = P.z_rd[b];
            float c    = P.c_rd[j * 64 + b];
            float hold = P.h_rd[j * 64 + b];
            float ig   = i * g;
            float cupd = f * c + ig;
            float cnew = (zo_ != 0.0f) ? ig : ((zb_ != 0.0f) ? cupd : c);
            float hnew = (zo_ == 0.0f && zb_ == 0.0f) ? hold : (o * tanhf(cnew));
            P.c_wr[j * 64 + b] = cnew;
            P.h_wr[j * 64 + b] = hnew;
            P.out_h[((size_t)b * Tt + t) * (3 * Hh) + l * Hh + j] = hnew;
        }
    } else {
        const float* __restrict__ wbz = P.Wb + (size_t)1024 * KW;
        const float* __restrict__ wrz = P.Wr + (size_t)1024 * KW;
        const float* __restrict__ wtz = (l < 2) ? P.Wt + (size_t)1024 * KW : nullptr;
        const float* __restrict__ xrow = (l == 0) ? P.x + ((size_t)lane * Tt + t) * Hh : nullptr;
        double aB = 0.0, aR = 0.0, aT = 0.0;
#pragma unroll 4
        for (int k = k0; k < k0 + 32; ++k) {
            float hbv = (l == 0) ? xrow[k] : P.hb_rd[k * 64 + lane];
            aB += (double)wbz[k] * (double)hbv;
            aR += (double)wrz[k] * (double)P.h_rd[k * 64 + lane];
            if (l < 2) aT += (double)wtz[k] * (double)P.ht_rd[k * 64 + lane];
        }
        zred[wv][0][lane] = aB; zred[wv][1][lane] = aR; zred[wv][2][lane] = aT;
        __syncthreads();
        if (tid < 64) {
            const int b = tid;
            double sB = 0.0, sR = 0.0, sT = 0.0;
#pragma unroll
            for (int v = 0; v < 8; ++v) {
                sB += zred[v][0][b]; sR += zred[v][1][b]; sT += zred[v][2][b];
            }
            double zb_ = (l == 0) ? 1.0 : (double)P.zb_rd[b];
            double zo_ = (double)P.z_rd[b];
            double s = (double)P.bias[1024] + zb_ * sB + sR + zo_ * sT;
            float znew = (s > 0.0) ? 1.0f : 0.0f;
            P.z_wr[b] = znew;
            P.out_z[((size_t)b * Tt + t) * 3 + l] = znew;
        }
    }
}

extern "C" void kernel_launch(void* const* d_in, const int* in_sizes, int n_in,
                              void* d_out, int out_size, void* d_ws, size_t ws_size,
                              hipStream_t stream) {
    (void)in_sizes; (void)n_in; (void)out_size;

    const float* x = (const float*)d_in[0];
    // dict order: x, Wb0,Wr0,Wt0,b0, Wb1,Wr1,Wt1,b1, Wb2,Wr2,Wt2,b2
    float* wsf = (float*)d_ws;

    // ws layout (floats)
    const size_t OFF_CT   = 8 * (size_t)MATF;          // fallback c [2][3][16384]
    const size_t OFF_ZS   = OFF_CT + 2 * 3 * Hh * Bb;  // fallback z (float[384])
    const size_t OFF_ZA   = OFF_ZS + 384;              // 1539 z masks x 64 floats (256B)
    const size_t OFF_BAR  = OFF_ZA + (size_t)1539 * 64;
    const size_t OFF_HALL = OFF_BAR + 4096;            // 513*3 slots x SLOTF
    const size_t OFF_END  = OFF_HALL + (size_t)513 * 3 * SLOTF;

    float* WT = wsf;
    float* cT = wsf + OFF_CT;
    float* zS = wsf + OFF_ZS;
    unsigned long long* zA = (unsigned long long*)(wsf + OFF_ZA);
    unsigned int* bar = (unsigned int*)(wsf + OFF_BAR);
    float* hAll = wsf + OFF_HALL;

    const bool canCoop = ws_size >= OFF_END * sizeof(float);

    // Zero mutable state: fallback c/z, z masks, barrier region, first 6 h
    // slots (t=0 reads slots 0..2 + freshly-written 3..5; zA entries 0..2).
    hipMemsetAsync(cT, 0, (OFF_HALL - OFF_CT) * sizeof(float), stream);
    size_t hZero = canCoop ? (size_t)6 * SLOTF : (size_t)2 * 3 * Hh * Bb;
    hipMemsetAsync(hAll, 0, hZero * sizeof(float), stream);

    Ptrs8 ps;
    const int mi[8] = { 1, 2, 3, 5, 6, 7, 9, 10 };  // Wb0,Wr0,Wt0,Wb1,Wr1,Wt1,Wb2,Wr2
    for (int i = 0; i < 8; ++i) ps.p[i] = (const float*)d_in[mi[i]];
    transpose_w<<<dim3(256, 8), 256, 0, stream>>>(ps, WT);

    float* out_h = (float*)d_out;
    float* out_z = out_h + (size_t)Bb * Tt * (3 * Hh);

    if (canCoop) {
        PK pk;
        pk.x = x;
        for (int i = 0; i < 8; ++i) pk.W[i] = WT + (size_t)i * MATF;
        pk.bias[0] = (const float*)d_in[4];
        pk.bias[1] = (const float*)d_in[8];
        pk.bias[2] = (const float*)d_in[12];
        pk.hAll = hAll; pk.zA = zA; pk.bar = bar;
        pk.out_h = out_h;
        pk.out_z = out_z;
        void* args[] = { &pk };
        hipError_t e = hipLaunchCooperativeKernel((void*)persistent_kernel,
                                                  dim3(256), dim3(512), args, 0, stream);
        if (e == hipSuccess) return;
    }

    // -------- fallback: proven 1536-launch path --------
    float* hT = hAll;   // [2][3][16384] ping-pong (zeroed above)
    const int wmb[3] = { 0, 3, 6 };
    const int wmr[3] = { 1, 4, 7 };
    const int wmt[3] = { 2, 5, -1 };

    auto hS = [&](int pp, int ll) { return hT + ((size_t)pp * 3 + ll) * (Hh * Bb); };
    auto cS = [&](int pp, int ll) { return cT + ((size_t)pp * 3 + ll) * (Hh * Bb); };
    auto zSl = [&](int pp, int ll) { return zS + ((size_t)pp * 3 + ll) * Bb; };

    for (int t = 0; t < Tt; ++t) {
        int p = t & 1;
        for (int l = 0; l < 3; ++l) {
            StageP P;
            P.x    = (l == 0) ? x : nullptr;
            P.Wb   = WT + (size_t)wmb[l] * MATF;
            P.Wr   = WT + (size_t)wmr[l] * MATF;
            P.Wt   = (l < 2) ? WT + (size_t)wmt[l] * MATF : nullptr;
            P.bias = (l == 0) ? (const float*)d_in[4] : (l == 1) ? (const float*)d_in[8] : (const float*)d_in[12];
            P.h_rd  = hS(p, l);
            P.ht_rd = (l < 2) ? hS(p, l + 1) : nullptr;
            P.hb_rd = (l > 0) ? hS(p ^ 1, l - 1) : nullptr;
            P.c_rd  = cS(p, l);
            P.c_wr  = cS(p ^ 1, l);
            P.z_rd  = zSl(p, l);
            P.zb_rd = (l > 0) ? zSl(p ^ 1, l - 1) : nullptr;
            P.h_wr  = hS(p ^ 1, l);
            P.z_wr  = zSl(p ^ 1, l);
            P.out_h = out_h;
            P.out_z = out_z;
            P.t     = t;
            P.layer = l;
            stage_kernel<<<257, 512, 0, stream>>>(P);
        }
    }
}

// Round 10
// 29435.712 us; speedup vs baseline: 3.1387x; 1.4557x over previous
//
#include <hip/hip_runtime.h>
#include <cmath>

// HM-LSTM forward, MI355X. Round 9: optimized MULTI-LAUNCH (no grid sync).
// 8 rounds of persistent-kernel barriers all landed at ~25us/stage or broke
// (cg::sync L2-flush; atomic-RMW trees; sc0-poll stale-L1 deadlock; flag-scan
// replay-unsafe). The 1536-launch path is proven correct + replay-safe at
// 25.9us/stage; this round optimizes the stage kernel itself:
//  - x pre-transposed to xT[t][k][b]: l0 bottom reads become coalesced 256B
//    wave loads (was 64-way uncoalesced, 512KB lane stride).
//  - float4 weight loads (4 k per instr, static-index arrays -> registers).
//  - No scattered out_h writes in stages: h -> unique per-stage hAll slots
//    (coalesced, NORMAL stores; kernel-boundary coherence), z -> ballot masks
//    in zA; final expansion kernel does the coalesced transpose into d_out.
//  - Grid 256 exactly (1 WG/CU, no 257th-WG tail): z column fused into WG0's
//    gate k-loop (reuses loaded h; +3 fp64 MACs/k -> WG0 ~1.3x others).
//  - z stays fp64 accum, s>0 binarization (matches numpy fp32 boundary;
//    proven over 5 passing rounds).

#define Hh    256
#define Bb    64
#define Tt    512
#define GC    1025
#define KW    256
#define MATF  (GC * KW)          // 262400 floats per transposed matrix
#define SLOTF (Hh * Bb + 32)     // 16416 floats: 64KB slot + 128B pad
#define ZSTR  32                 // uint64 stride per z entry (256B padded)

struct Ptrs8 { const float* p[8]; };

__global__ __launch_bounds__(256) void transpose_w(Ptrs8 srcs, float* __restrict__ dst) {
    int k = blockIdx.x;                    // 0..255 (row of source = K index)
    int m = blockIdx.y;                    // 0..7   (matrix)
    const float* __restrict__ src = srcs.p[m];
    float* __restrict__ d = dst + (size_t)m * MATF;
#pragma unroll
    for (int c = 0; c < 5; ++c) {
        int col = c * 256 + threadIdx.x;
        if (col < GC) d[(size_t)col * KW + k] = src[(size_t)k * GC + col];
    }
}

// x (B,T,K) -> xT[t][k][b]
__global__ __launch_bounds__(256) void transpose_x(const float* __restrict__ x,
                                                   float* __restrict__ xT) {
    __shared__ float tile[64][65];
    const int t    = blockIdx.x;
    const int lane = threadIdx.x & 63;
    const int w    = threadIdx.x >> 6;    // 0..3
#pragma unroll 1
    for (int kt = 0; kt < 4; ++kt) {
        const int kbase = kt * 64;
        __syncthreads();
#pragma unroll
        for (int r = 0; r < 16; ++r) {
            const int b = w * 16 + r;
            tile[b][lane] = x[((size_t)b * Tt + t) * Hh + kbase + lane];
        }
        __syncthreads();
#pragma unroll
        for (int r = 0; r < 16; ++r) {
            const int kk = w * 16 + r;
            xT[((size_t)t * Hh + kbase + kk) * 64 + lane] = tile[lane][kk];
        }
    }
}

// ---------------------------------------------------------------------------
// Stage kernel: one (t,l) cell update. Grid 256 x 512. WG j computes gate
// columns {j,256+j,512+j,768+j}; WG 0 additionally fuses the z column.
// ---------------------------------------------------------------------------
struct StageP {
    const float* bot;    // [k*64+b] bottom stream (xT row or h slot); null -> use x
    const float* x;      // raw x (only when bot == null, l==0 no-xT tier)
    const float* h;      // own h slot (t*3+l)
    const float* top;    // top slot or null (l==2)
    const float* Wb;
    const float* Wr;
    const float* Wt;     // null for l==2
    const float* bias;
    const float* c_rd;
    float*       c_wr;
    const unsigned long long* zm0;  // own prev z mask
    const unsigned long long* zm1;  // below z mask; null -> all-ones (l==0)
    float*       h_wr;   // slot (t+1)*3+l
    unsigned long long* zm_wr;
    int t;
};

__global__ __launch_bounds__(512) void stage_kernel(StageP P) {
    __shared__ float  sred[8][4][64];
    __shared__ double zred[8][3][64];
    __shared__ unsigned long long smask[2];

    const int tid  = threadIdx.x;
    const int lane = tid & 63;    // batch row
    const int wv   = tid >> 6;    // 0..7, K chunk
    const int wg   = blockIdx.x;  // gate column j
    const int k0   = wv * 32;

    if (tid == 0)  smask[0] = *P.zm0;
    if (tid == 64) smask[1] = P.zm1 ? *P.zm1 : ~0ull;
    __syncthreads();
    const float zo = (float)((smask[0] >> lane) & 1ull);
    const float zb = (float)((smask[1] >> lane) & 1ull);
    const bool hasT = (P.top != nullptr);
    const int j = wg;

    const float* __restrict__ wb0 = P.Wb + (size_t)(0 * Hh + j) * KW;
    const float* __restrict__ wb1 = P.Wb + (size_t)(1 * Hh + j) * KW;
    const float* __restrict__ wb2 = P.Wb + (size_t)(2 * Hh + j) * KW;
    const float* __restrict__ wb3 = P.Wb + (size_t)(3 * Hh + j) * KW;
    const float* __restrict__ wr0 = P.Wr + (size_t)(0 * Hh + j) * KW;
    const float* __restrict__ wr1 = P.Wr + (size_t)(1 * Hh + j) * KW;
    const float* __restrict__ wr2 = P.Wr + (size_t)(2 * Hh + j) * KW;
    const float* __restrict__ wr3 = P.Wr + (size_t)(3 * Hh + j) * KW;
    const float* __restrict__ wt0 = hasT ? P.Wt + (size_t)(0 * Hh + j) * KW : nullptr;
    const float* __restrict__ wt1 = hasT ? P.Wt + (size_t)(1 * Hh + j) * KW : nullptr;
    const float* __restrict__ wt2 = hasT ? P.Wt + (size_t)(2 * Hh + j) * KW : nullptr;
    const float* __restrict__ wt3 = hasT ? P.Wt + (size_t)(3 * Hh + j) * KW : nullptr;

    float a0 = 0.f, a1 = 0.f, a2 = 0.f, a3 = 0.f;
    double aB = 0.0, aR = 0.0, aT = 0.0;   // WG0 z partials

    if (P.bot) {
        const float* __restrict__ bot = P.bot;
        const float* __restrict__ h   = P.h;
        const float* __restrict__ top = P.top;
        if (wg != 0) {
#pragma unroll 2
            for (int k4 = k0; k4 < k0 + 32; k4 += 4) {
                float wB0[4], wB1[4], wB2[4], wB3[4];
                float wR0[4], wR1[4], wR2[4], wR3[4];
                float wT0[4], wT1[4], wT2[4], wT3[4];
                *(float4*)wB0 = *(const float4*)(wb0 + k4);
                *(float4*)wB1 = *(const float4*)(wb1 + k4);
                *(float4*)wB2 = *(const float4*)(wb2 + k4);
                *(float4*)wB3 = *(const float4*)(wb3 + k4);
                *(float4*)wR0 = *(const float4*)(wr0 + k4);
                *(float4*)wR1 = *(const float4*)(wr1 + k4);
                *(float4*)wR2 = *(const float4*)(wr2 + k4);
                *(float4*)wR3 = *(const float4*)(wr3 + k4);
                if (hasT) {
                    *(float4*)wT0 = *(const float4*)(wt0 + k4);
                    *(float4*)wT1 = *(const float4*)(wt1 + k4);
                    *(float4*)wT2 = *(const float4*)(wt2 + k4);
                    *(float4*)wT3 = *(const float4*)(wt3 + k4);
                }
#pragma unroll
                for (int s = 0; s < 4; ++s) {
                    const int k = k4 + s;
                    float hbz = zb * bot[k * 64 + lane];
                    float hv  = h[k * 64 + lane];
                    a0 += wB0[s] * hbz + wR0[s] * hv;
                    a1 += wB1[s] * hbz + wR1[s] * hv;
                    a2 += wB2[s] * hbz + wR2[s] * hv;
                    a3 += wB3[s] * hbz + wR3[s] * hv;
                    if (hasT) {
                        float htz = zo * top[k * 64 + lane];
                        a0 += wT0[s] * htz; a1 += wT1[s] * htz;
                        a2 += wT2[s] * htz; a3 += wT3[s] * htz;
                    }
                }
            }
        } else {
            // WG 0: gates + fused z column (fp64)
            const float* __restrict__ wbz = P.Wb + (size_t)1024 * KW;
            const float* __restrict__ wrz = P.Wr + (size_t)1024 * KW;
            const float* __restrict__ wtz = hasT ? P.Wt + (size_t)1024 * KW : nullptr;
#pragma unroll 2
            for (int k4 = k0; k4 < k0 + 32; k4 += 4) {
                float wB0[4], wB1[4], wB2[4], wB3[4];
                float wR0[4], wR1[4], wR2[4], wR3[4];
                float wT0[4], wT1[4], wT2[4], wT3[4];
                float wZb[4], wZr[4], wZt[4];
                *(float4*)wB0 = *(const float4*)(wb0 + k4);
                *(float4*)wB1 = *(const float4*)(wb1 + k4);
                *(float4*)wB2 = *(const float4*)(wb2 + k4);
                *(float4*)wB3 = *(const float4*)(wb3 + k4);
                *(float4*)wR0 = *(const float4*)(wr0 + k4);
                *(float4*)wR1 = *(const float4*)(wr1 + k4);
                *(float4*)wR2 = *(const float4*)(wr2 + k4);
                *(float4*)wR3 = *(const float4*)(wr3 + k4);
                *(float4*)wZb = *(const float4*)(wbz + k4);
                *(float4*)wZr = *(const float4*)(wrz + k4);
                if (hasT) {
                    *(float4*)wT0 = *(const float4*)(wt0 + k4);
                    *(float4*)wT1 = *(const float4*)(wt1 + k4);
                    *(float4*)wT2 = *(const float4*)(wt2 + k4);
                    *(float4*)wT3 = *(const float4*)(wt3 + k4);
                    *(float4*)wZt = *(const float4*)(wtz + k4);
                }
#pragma unroll
                for (int s = 0; s < 4; ++s) {
                    const int k = k4 + s;
                    float hbv = bot[k * 64 + lane];
                    float hbz = zb * hbv;
                    float hv  = h[k * 64 + lane];
                    a0 += wB0[s] * hbz + wR0[s] * hv;
                    a1 += wB1[s] * hbz + wR1[s] * hv;
                    a2 += wB2[s] * hbz + wR2[s] * hv;
                    a3 += wB3[s] * hbz + wR3[s] * hv;
                    aB += (double)wZb[s] * (double)hbv;
                    aR += (double)wZr[s] * (double)hv;
                    if (hasT) {
                        float htv = top[k * 64 + lane];
                        float htz = zo * htv;
                        a0 += wT0[s] * htz; a1 += wT1[s] * htz;
                        a2 += wT2[s] * htz; a3 += wT3[s] * htz;
                        aT += (double)wZt[s] * (double)htv;
                    }
                }
            }
        }
    } else {
        // l==0 without xT: per-lane x rows (r1-proven), scalar weights.
        const float4* __restrict__ xp =
            (const float4*)(P.x + ((size_t)lane * Tt + P.t) * Hh + k0);
        float xr[32];
#pragma unroll
        for (int q = 0; q < 8; ++q) {
            float4 v = xp[q];
            xr[4 * q + 0] = v.x; xr[4 * q + 1] = v.y;
            xr[4 * q + 2] = v.z; xr[4 * q + 3] = v.w;
        }
        const float* __restrict__ h   = P.h;
        const float* __restrict__ top = P.top;
        if (wg != 0) {
#pragma unroll
            for (int kk = 0; kk < 32; ++kk) {
                const int k = k0 + kk;
                float hbz = xr[kk];               // z_bottom == 1 exactly
                float hv  = h[k * 64 + lane];
                float htz = zo * top[k * 64 + lane];
                a0 += wb0[k] * hbz + wr0[k] * hv + wt0[k] * htz;
                a1 += wb1[k] * hbz + wr1[k] * hv + wt1[k] * htz;
                a2 += wb2[k] * hbz + wr2[k] * hv + wt2[k] * htz;
                a3 += wb3[k] * hbz + wr3[k] * hv + wt3[k] * htz;
            }
        } else {
            const float* __restrict__ wbz = P.Wb + (size_t)1024 * KW;
            const float* __restrict__ wrz = P.Wr + (size_t)1024 * KW;
            const float* __restrict__ wtz = P.Wt + (size_t)1024 * KW;
#pragma unroll
            for (int kk = 0; kk < 32; ++kk) {
                const int k = k0 + kk;
                float hbv = xr[kk];
                float hv  = h[k * 64 + lane];
                float htv = top[k * 64 + lane];
                float htz = zo * htv;
                a0 += wb0[k] * hbv + wr0[k] * hv + wt0[k] * htz;
                a1 += wb1[k] * hbv + wr1[k] * hv + wt1[k] * htz;
                a2 += wb2[k] * hbv + wr2[k] * hv + wt2[k] * htz;
                a3 += wb3[k] * hbv + wr3[k] * hv + wt3[k] * htz;
                aB += (double)wbz[k] * (double)hbv;
                aR += (double)wrz[k] * (double)hv;
                aT += (double)wtz[k] * (double)htv;
            }
        }
    }

    sred[wv][0][lane] = a0; sred[wv][1][lane] = a1;
    sred[wv][2][lane] = a2; sred[wv][3][lane] = a3;
    if (wg == 0) {
        zred[wv][0][lane] = aB; zred[wv][1][lane] = aR; zred[wv][2][lane] = aT;
    }
    __syncthreads();
    if (tid < 64) {
        const int b = tid;
        float s0 = P.bias[0 * Hh + j];
        float s1 = P.bias[1 * Hh + j];
        float s2 = P.bias[2 * Hh + j];
        float s3 = P.bias[3 * Hh + j];
#pragma unroll
        for (int v = 0; v < 8; ++v) {
            s0 += sred[v][0][b]; s1 += sred[v][1][b];
            s2 += sred[v][2][b]; s3 += sred[v][3][b];
        }
        float f = 1.0f / (1.0f + expf(-s0));
        float i = 1.0f / (1.0f + expf(-s1));
        float o = 1.0f / (1.0f + expf(-s2));
        float g = tanhf(s3);
        float zb_ = (float)((smask[1] >> b) & 1ull);
        float zo_ = (float)((smask[0] >> b) & 1ull);
        float c    = P.c_rd[j * 64 + b];
        float hold = P.h[j * 64 + b];
        float ig   = i * g;
        float cupd = f * c + ig;
        // z, zb in {0,1} exactly -> selects == reference arithmetic
        float cnew = (zo_ != 0.0f) ? ig : ((zb_ != 0.0f) ? cupd : c);
        float hnew = (zo_ == 0.0f && zb_ == 0.0f) ? hold : (o * tanhf(cnew));
        P.c_wr[j * 64 + b] = cnew;
        P.h_wr[j * 64 + b] = hnew;
        if (wg == 0) {
            double sB = 0.0, sR = 0.0, sT = 0.0;
#pragma unroll
            for (int v = 0; v < 8; ++v) {
                sB += zred[v][0][b]; sR += zred[v][1][b]; sT += zred[v][2][b];
            }
            double s = (double)P.bias[1024] + (double)zb_ * sB + sR + (double)zo_ * sT;
            // round(clip((s+1)/2,0,1)) with round-half-even == (s > 0)
            float znew = (s > 0.0) ? 1.0f : 0.0f;
            unsigned long long m = __ballot(znew != 0.0f);
            if (b == 0) *P.zm_wr = m;
        }
    }
}

// ---------------------------------------------------------------------------
// Final expansion: hAll/zA -> d_out (coalesced LDS transpose). Grid 256 x 512.
// ---------------------------------------------------------------------------
__global__ __launch_bounds__(512) void expand_out(const float* __restrict__ hAll,
                                                  const unsigned long long* __restrict__ zA,
                                                  float* __restrict__ out_h,
                                                  float* __restrict__ out_z) {
    __shared__ float tlds[64][65];
    const int tid  = threadIdx.x;
    const int lane = tid & 63;
    const int wv   = tid >> 6;
    const int wg   = blockIdx.x;

#pragma unroll 1
    for (int tt = 0; tt < 2; ++tt) {
        const int t = wg * 2 + tt;
#pragma unroll 1
        for (int l = 0; l < 3; ++l) {
            const float* __restrict__ slot = hAll + ((size_t)(t + 1) * 3 + l) * SLOTF;
#pragma unroll 1
            for (int jc = 0; jc < 4; ++jc) {
                __syncthreads();
                {   // load 64j x 64b chunk -> LDS (coalesced float4 x2)
                    const int f = tid * 8;
                    const int j = f >> 6;
                    const int b = f & 63;
                    const float* src = slot + (size_t)(jc * 64 + j) * 64 + b;
                    float4 v0 = *(const float4*)(src);
                    float4 v1 = *(const float4*)(src + 4);
                    float* d = &tlds[j][b];
                    d[0] = v0.x; d[1] = v0.y; d[2] = v0.z; d[3] = v0.w;
                    d[4] = v1.x; d[5] = v1.y; d[6] = v1.z; d[7] = v1.w;
                }
                __syncthreads();
#pragma unroll
                for (int it = 0; it < 8; ++it) {
                    const int b = wv + it * 8;
                    out_h[((size_t)b * Tt + t) * (3 * Hh) + l * 256 + jc * 64 + lane]
                        = tlds[lane][b];
                }
            }
        }
    }
    if (wg == 0) {
        for (int f = tid; f < Bb * Tt * 3; f += 512) {
            const int b  = f / (Tt * 3);
            const int r  = f % (Tt * 3);
            const int t2 = r / 3;
            const int l2 = r % 3;
            const unsigned long long m = zA[(size_t)((t2 + 1) * 3 + l2) * ZSTR];
            out_z[f] = (float)((m >> b) & 1ull);
        }
    }
}

extern "C" void kernel_launch(void* const* d_in, const int* in_sizes, int n_in,
                              void* d_out, int out_size, void* d_ws, size_t ws_size,
                              hipStream_t stream) {
    (void)in_sizes; (void)n_in; (void)out_size;

    const float* x = (const float*)d_in[0];
    // dict order: x, Wb0,Wr0,Wt0,b0, Wb1,Wr1,Wt1,b1, Wb2,Wr2,Wt2,b2
    const float* biases[3] = { (const float*)d_in[4], (const float*)d_in[8],
                               (const float*)d_in[12] };
    float* wsf = (float*)d_ws;

    // ws layout (floats)
    const size_t OFF_CT   = 8 * (size_t)MATF;            // c ping-pong [2][3][16384]
    const size_t OFF_ZA   = OFF_CT + 2 * 3 * Hh * Bb;    // 1539 z masks x 64 floats
    const size_t OFF_HALL = OFF_ZA + (size_t)1539 * 64;  // 513*3 slots x SLOTF
    const size_t OFF_XT   = OFF_HALL + (size_t)513 * 3 * SLOTF;
    const size_t OFF_END  = OFF_XT + (size_t)Tt * Hh * Bb;

    float* WT   = wsf;
    float* cT   = wsf + OFF_CT;
    unsigned long long* zA = (unsigned long long*)(wsf + OFF_ZA);
    float* hAll = wsf + OFF_HALL;
    float* xT   = wsf + OFF_XT;

    const bool canSlots = ws_size >= (OFF_HALL + (size_t)513 * 3 * SLOTF) * sizeof(float);
    const bool canXT    = ws_size >= OFF_END * sizeof(float);

    // Zero mutable state: c, z masks, first 6 h slots (zero initial state).
    hipMemsetAsync(cT, 0, (OFF_HALL - OFF_CT) * sizeof(float), stream);
    hipMemsetAsync(hAll, 0, (size_t)6 * SLOTF * sizeof(float), stream);

    Ptrs8 ps;
    const int mi[8] = { 1, 2, 3, 5, 6, 7, 9, 10 };  // Wb0,Wr0,Wt0,Wb1,Wr1,Wt1,Wb2,Wr2
    for (int i = 0; i < 8; ++i) ps.p[i] = (const float*)d_in[mi[i]];
    transpose_w<<<dim3(256, 8), 256, 0, stream>>>(ps, WT);
    if (canXT) transpose_x<<<512, 256, 0, stream>>>(x, xT);

    float* out_h = (float*)d_out;
    float* out_z = out_h + (size_t)Bb * Tt * (3 * Hh);

    const int wmb[3] = { 0, 3, 6 };
    const int wmr[3] = { 1, 4, 7 };
    const int wmt[3] = { 2, 5, -1 };

    if (canSlots) {
        auto slot = [&](int tIdx, int ll) { return hAll + ((size_t)tIdx * 3 + ll) * SLOTF; };
        for (int t = 0; t < Tt; ++t) {
            for (int l = 0; l < 3; ++l) {
                StageP P;
                P.bot  = (l == 0) ? (canXT ? xT + (size_t)t * Hh * 64 : nullptr)
                                  : slot(t + 1, l - 1);
                P.x    = (l == 0) ? x : nullptr;
                P.h    = slot(t, l);
                P.top  = (l < 2) ? slot(t, l + 1) : nullptr;
                P.Wb   = WT + (size_t)wmb[l] * MATF;
                P.Wr   = WT + (size_t)wmr[l] * MATF;
                P.Wt   = (l < 2) ? WT + (size_t)wmt[l] * MATF : nullptr;
                P.bias = biases[l];
                P.c_rd = cT + (size_t)((t & 1) * 3 + l) * (Hh * Bb);
                P.c_wr = cT + (size_t)(((t & 1) ^ 1) * 3 + l) * (Hh * Bb);
                P.zm0  = &zA[(size_t)(t * 3 + l) * ZSTR];
                P.zm1  = (l > 0) ? &zA[(size_t)((t + 1) * 3 + l - 1) * ZSTR] : nullptr;
                P.h_wr = slot(t + 1, l);
                P.zm_wr = &zA[(size_t)((t + 1) * 3 + l) * ZSTR];
                P.t    = t;
                stage_kernel<<<256, 512, 0, stream>>>(P);
            }
        }
        expand_out<<<256, 512, 0, stream>>>(hAll, zA, out_h, out_z);
        return;
    }

    // -------- minimal fallback (ws too small for slots): ping-pong h in the
    // hAll area, direct x reads, direct out writes via expansion skipped ----
    // Use the slot machinery with a 2-deep window is unsafe; instead run the
    // same stage kernel with ping-pong slots and per-stage d_out expansion
    // folded into a tiny copy at the end is not possible -> emulate r0:
    // reuse stage_kernel with slots aliased into a [4] ring would violate
    // uniqueness; given harness ws (proven >=110MB in r5..r8), this branch
    // is effectively dead. Launch nothing rather than risk corruption.
    (void)wmt;
}

// Round 11
// 29298.013 us; speedup vs baseline: 3.1535x; 1.0047x over previous
//
#include <hip/hip_runtime.h>
#include <cmath>

// HM-LSTM forward, MI355X. Round 10: DIAGONAL-SKEW multi-launch.
// r10 proved the optimized multi-launch at 29.4ms (19.1us/stage) with a large
// fixed per-launch cost. The DAG admits level function k = 2t + l: deps of
// (t,l) land at k-2 ((t-1,l)), k-1 ((t,l-1)), k-1 ((t-1,l+1)) -> stages
// (l0@t, l2@t-1) at even k are independent and share ONE launch (512 WGs).
// 1536 -> 1025 launches (= DAG critical path, the multi-launch minimum).
// Stage body is byte-identical to r10's proven kernel (device function).
//  - x pre-transposed xT[t][k][b]; float4 weight loads; h -> unique per-stage
//    hAll slots (normal stores, kernel-boundary coherence); z ballot masks in
//    zA; final expand kernel; z fp64 accum, s>0 (proven 6 passing rounds).

#define Hh    256
#define Bb    64
#define Tt    512
#define GC    1025
#define KW    256
#define MATF  (GC * KW)          // 262400 floats per transposed matrix
#define SLOTF (Hh * Bb + 32)     // 16416 floats: 64KB slot + 128B pad
#define ZSTR  32                 // uint64 stride per z entry (256B padded)

struct Ptrs8 { const float* p[8]; };

__global__ __launch_bounds__(256) void transpose_w(Ptrs8 srcs, float* __restrict__ dst) {
    int k = blockIdx.x;                    // 0..255 (row of source = K index)
    int m = blockIdx.y;                    // 0..7   (matrix)
    const float* __restrict__ src = srcs.p[m];
    float* __restrict__ d = dst + (size_t)m * MATF;
#pragma unroll
    for (int c = 0; c < 5; ++c) {
        int col = c * 256 + threadIdx.x;
        if (col < GC) d[(size_t)col * KW + k] = src[(size_t)k * GC + col];
    }
}

// x (B,T,K) -> xT[t][k][b]
__global__ __launch_bounds__(256) void transpose_x(const float* __restrict__ x,
                                                   float* __restrict__ xT) {
    __shared__ float tile[64][65];
    const int t    = blockIdx.x;
    const int lane = threadIdx.x & 63;
    const int w    = threadIdx.x >> 6;    // 0..3
#pragma unroll 1
    for (int kt = 0; kt < 4; ++kt) {
        const int kbase = kt * 64;
        __syncthreads();
#pragma unroll
        for (int r = 0; r < 16; ++r) {
            const int b = w * 16 + r;
            tile[b][lane] = x[((size_t)b * Tt + t) * Hh + kbase + lane];
        }
        __syncthreads();
#pragma unroll
        for (int r = 0; r < 16; ++r) {
            const int kk = w * 16 + r;
            xT[((size_t)t * Hh + kbase + kk) * 64 + lane] = tile[lane][kk];
        }
    }
}

// ---------------------------------------------------------------------------
// Stage body (r10-proven): one (t,l) cell update for gate column wg.
// wg 0 additionally fuses the z column (fp64).
// ---------------------------------------------------------------------------
struct StageP {
    const float* bot;    // [k*64+b] bottom stream (xT row or h slot); null -> use x
    const float* x;      // raw x (only when bot == null, l==0 no-xT tier)
    const float* h;      // own h slot (t*3+l)
    const float* top;    // top slot or null (l==2)
    const float* Wb;
    const float* Wr;
    const float* Wt;     // null for l==2
    const float* bias;
    const float* c_rd;
    float*       c_wr;
    const unsigned long long* zm0;  // own prev z mask
    const unsigned long long* zm1;  // below z mask; null -> all-ones (l==0)
    float*       h_wr;   // slot (t+1)*3+l
    unsigned long long* zm_wr;
    int t;
};

__device__ __forceinline__ void stage_body(const StageP& P, int wg) {
    __shared__ float  sred[8][4][64];
    __shared__ double zred[8][3][64];
    __shared__ unsigned long long smask[2];

    const int tid  = threadIdx.x;
    const int lane = tid & 63;    // batch row
    const int wv   = tid >> 6;    // 0..7, K chunk
    const int k0   = wv * 32;

    if (tid == 0)  smask[0] = *P.zm0;
    if (tid == 64) smask[1] = P.zm1 ? *P.zm1 : ~0ull;
    __syncthreads();
    const float zo = (float)((smask[0] >> lane) & 1ull);
    const float zb = (float)((smask[1] >> lane) & 1ull);
    const bool hasT = (P.top != nullptr);
    const int j = wg;

    const float* __restrict__ wb0 = P.Wb + (size_t)(0 * Hh + j) * KW;
    const float* __restrict__ wb1 = P.Wb + (size_t)(1 * Hh + j) * KW;
    const float* __restrict__ wb2 = P.Wb + (size_t)(2 * Hh + j) * KW;
    const float* __restrict__ wb3 = P.Wb + (size_t)(3 * Hh + j) * KW;
    const float* __restrict__ wr0 = P.Wr + (size_t)(0 * Hh + j) * KW;
    const float* __restrict__ wr1 = P.Wr + (size_t)(1 * Hh + j) * KW;
    const float* __restrict__ wr2 = P.Wr + (size_t)(2 * Hh + j) * KW;
    const float* __restrict__ wr3 = P.Wr + (size_t)(3 * Hh + j) * KW;
    const float* __restrict__ wt0 = hasT ? P.Wt + (size_t)(0 * Hh + j) * KW : nullptr;
    const float* __restrict__ wt1 = hasT ? P.Wt + (size_t)(1 * Hh + j) * KW : nullptr;
    const float* __restrict__ wt2 = hasT ? P.Wt + (size_t)(2 * Hh + j) * KW : nullptr;
    const float* __restrict__ wt3 = hasT ? P.Wt + (size_t)(3 * Hh + j) * KW : nullptr;

    float a0 = 0.f, a1 = 0.f, a2 = 0.f, a3 = 0.f;
    double aB = 0.0, aR = 0.0, aT = 0.0;   // wg0 z partials

    if (P.bot) {
        const float* __restrict__ bot = P.bot;
        const float* __restrict__ h   = P.h;
        const float* __restrict__ top = P.top;
        if (wg != 0) {
#pragma unroll 2
            for (int k4 = k0; k4 < k0 + 32; k4 += 4) {
                float wB0[4], wB1[4], wB2[4], wB3[4];
                float wR0[4], wR1[4], wR2[4], wR3[4];
                float wT0[4], wT1[4], wT2[4], wT3[4];
                *(float4*)wB0 = *(const float4*)(wb0 + k4);
                *(float4*)wB1 = *(const float4*)(wb1 + k4);
                *(float4*)wB2 = *(const float4*)(wb2 + k4);
                *(float4*)wB3 = *(const float4*)(wb3 + k4);
                *(float4*)wR0 = *(const float4*)(wr0 + k4);
                *(float4*)wR1 = *(const float4*)(wr1 + k4);
                *(float4*)wR2 = *(const float4*)(wr2 + k4);
                *(float4*)wR3 = *(const float4*)(wr3 + k4);
                if (hasT) {
                    *(float4*)wT0 = *(const float4*)(wt0 + k4);
                    *(float4*)wT1 = *(const float4*)(wt1 + k4);
                    *(float4*)wT2 = *(const float4*)(wt2 + k4);
                    *(float4*)wT3 = *(const float4*)(wt3 + k4);
                }
#pragma unroll
                for (int s = 0; s < 4; ++s) {
                    const int k = k4 + s;
                    float hbz = zb * bot[k * 64 + lane];
                    float hv  = h[k * 64 + lane];
                    a0 += wB0[s] * hbz + wR0[s] * hv;
                    a1 += wB1[s] * hbz + wR1[s] * hv;
                    a2 += wB2[s] * hbz + wR2[s] * hv;
                    a3 += wB3[s] * hbz + wR3[s] * hv;
                    if (hasT) {
                        float htz = zo * top[k * 64 + lane];
                        a0 += wT0[s] * htz; a1 += wT1[s] * htz;
                        a2 += wT2[s] * htz; a3 += wT3[s] * htz;
                    }
                }
            }
        } else {
            const float* __restrict__ wbz = P.Wb + (size_t)1024 * KW;
            const float* __restrict__ wrz = P.Wr + (size_t)1024 * KW;
            const float* __restrict__ wtz = hasT ? P.Wt + (size_t)1024 * KW : nullptr;
#pragma unroll 2
            for (int k4 = k0; k4 < k0 + 32; k4 += 4) {
                float wB0[4], wB1[4], wB2[4], wB3[4];
                float wR0[4], wR1[4], wR2[4], wR3[4];
                float wT0[4], wT1[4], wT2[4], wT3[4];
                float wZb[4], wZr[4], wZt[4];
                *(float4*)wB0 = *(const float4*)(wb0 + k4);
                *(float4*)wB1 = *(const float4*)(wb1 + k4);
                *(float4*)wB2 = *(const float4*)(wb2 + k4);
                *(float4*)wB3 = *(const float4*)(wb3 + k4);
                *(float4*)wR0 = *(const float4*)(wr0 + k4);
                *(float4*)wR1 = *(const float4*)(wr1 + k4);
                *(float4*)wR2 = *(const float4*)(wr2 + k4);
                *(float4*)wR3 = *(const float4*)(wr3 + k4);
                *(float4*)wZb = *(const float4*)(wbz + k4);
                *(float4*)wZr = *(const float4*)(wrz + k4);
                if (hasT) {
                    *(float4*)wT0 = *(const float4*)(wt0 + k4);
                    *(float4*)wT1 = *(const float4*)(wt1 + k4);
                    *(float4*)wT2 = *(const float4*)(wt2 + k4);
                    *(float4*)wT3 = *(const float4*)(wt3 + k4);
                    *(float4*)wZt = *(const float4*)(wtz + k4);
                }
#pragma unroll
                for (int s = 0; s < 4; ++s) {
                    const int k = k4 + s;
                    float hbv = bot[k * 64 + lane];
                    float hbz = zb * hbv;
                    float hv  = h[k * 64 + lane];
                    a0 += wB0[s] * hbz + wR0[s] * hv;
                    a1 += wB1[s] * hbz + wR1[s] * hv;
                    a2 += wB2[s] * hbz + wR2[s] * hv;
                    a3 += wB3[s] * hbz + wR3[s] * hv;
                    aB += (double)wZb[s] * (double)hbv;
                    aR += (double)wZr[s] * (double)hv;
                    if (hasT) {
                        float htv = top[k * 64 + lane];
                        float htz = zo * htv;
                        a0 += wT0[s] * htz; a1 += wT1[s] * htz;
                        a2 += wT2[s] * htz; a3 += wT3[s] * htz;
                        aT += (double)wZt[s] * (double)htv;
                    }
                }
            }
        }
    } else {
        // l==0 without xT: per-lane x rows (r1-proven), scalar weights.
        const float4* __restrict__ xp =
            (const float4*)(P.x + ((size_t)lane * Tt + P.t) * Hh + k0);
        float xr[32];
#pragma unroll
        for (int q = 0; q < 8; ++q) {
            float4 v = xp[q];
            xr[4 * q + 0] = v.x; xr[4 * q + 1] = v.y;
            xr[4 * q + 2] = v.z; xr[4 * q + 3] = v.w;
        }
        const float* __restrict__ h   = P.h;
        const float* __restrict__ top = P.top;
        if (wg != 0) {
#pragma unroll
            for (int kk = 0; kk < 32; ++kk) {
                const int k = k0 + kk;
                float hbz = xr[kk];               // z_bottom == 1 exactly
                float hv  = h[k * 64 + lane];
                float htz = zo * top[k * 64 + lane];
                a0 += wb0[k] * hbz + wr0[k] * hv + wt0[k] * htz;
                a1 += wb1[k] * hbz + wr1[k] * hv + wt1[k] * htz;
                a2 += wb2[k] * hbz + wr2[k] * hv + wt2[k] * htz;
                a3 += wb3[k] * hbz + wr3[k] * hv + wt3[k] * htz;
            }
        } else {
            const float* __restrict__ wbz = P.Wb + (size_t)1024 * KW;
            const float* __restrict__ wrz = P.Wr + (size_t)1024 * KW;
            const float* __restrict__ wtz = P.Wt + (size_t)1024 * KW;
#pragma unroll
            for (int kk = 0; kk < 32; ++kk) {
                const int k = k0 + kk;
                float hbv = xr[kk];
                float hv  = h[k * 64 + lane];
                float htv = top[k * 64 + lane];
                float htz = zo * htv;
                a0 += wb0[k] * hbv + wr0[k] * hv + wt0[k] * htz;
                a1 += wb1[k] * hbv + wr1[k] * hv + wt1[k] * htz;
                a2 += wb2[k] * hbv + wr2[k] * hv + wt2[k] * htz;
                a3 += wb3[k] * hbv + wr3[k] * hv + wt3[k] * htz;
                aB += (double)wbz[k] * (double)hbv;
                aR += (double)wrz[k] * (double)hv;
                aT += (double)wtz[k] * (double)htv;
            }
        }
    }

    sred[wv][0][lane] = a0; sred[wv][1][lane] = a1;
    sred[wv][2][lane] = a2; sred[wv][3][lane] = a3;
    if (wg == 0) {
        zred[wv][0][lane] = aB; zred[wv][1][lane] = aR; zred[wv][2][lane] = aT;
    }
    __syncthreads();
    if (tid < 64) {
        const int b = tid;
        float s0 = P.bias[0 * Hh + j];
        float s1 = P.bias[1 * Hh + j];
        float s2 = P.bias[2 * Hh + j];
        float s3 = P.bias[3 * Hh + j];
#pragma unroll
        for (int v = 0; v < 8; ++v) {
            s0 += sred[v][0][b]; s1 += sred[v][1][b];
            s2 += sred[v][2][b]; s3 += sred[v][3][b];
        }
        float f = 1.0f / (1.0f + expf(-s0));
        float i = 1.0f / (1.0f + expf(-s1));
        float o = 1.0f / (1.0f + expf(-s2));
        float g = tanhf(s3);
        float zb_ = (float)((smask[1] >> b) & 1ull);
        float zo_ = (float)((smask[0] >> b) & 1ull);
        float c    = P.c_rd[j * 64 + b];
        float hold = P.h[j * 64 + b];
        float ig   = i * g;
        float cupd = f * c + ig;
        // z, zb in {0,1} exactly -> selects == reference arithmetic
        float cnew = (zo_ != 0.0f) ? ig : ((zb_ != 0.0f) ? cupd : c);
        float hnew = (zo_ == 0.0f && zb_ == 0.0f) ? hold : (o * tanhf(cnew));
        P.c_wr[j * 64 + b] = cnew;
        P.h_wr[j * 64 + b] = hnew;
        if (wg == 0) {
            double sB = 0.0, sR = 0.0, sT = 0.0;
#pragma unroll
            for (int v = 0; v < 8; ++v) {
                sB += zred[v][0][b]; sR += zred[v][1][b]; sT += zred[v][2][b];
            }
            double s = (double)P.bias[1024] + (double)zb_ * sB + sR + (double)zo_ * sT;
            // round(clip((s+1)/2,0,1)) with round-half-even == (s > 0)
            float znew = (s > 0.0) ? 1.0f : 0.0f;
            unsigned long long m = __ballot(znew != 0.0f);
            if (b == 0) *P.zm_wr = m;
        }
    }
}

__global__ __launch_bounds__(512) void stage1_kernel(StageP A) {
    stage_body(A, blockIdx.x);
}

__global__ __launch_bounds__(512) void stage2_kernel(StageP A, StageP B) {
    const int wg = blockIdx.x;
    if (wg < 256) stage_body(A, wg);
    else          stage_body(B, wg - 256);
}

// ---------------------------------------------------------------------------
// Final expansion: hAll/zA -> d_out (coalesced LDS transpose). Grid 256 x 512.
// ---------------------------------------------------------------------------
__global__ __launch_bounds__(512) void expand_out(const float* __restrict__ hAll,
                                                  const unsigned long long* __restrict__ zA,
                                                  float* __restrict__ out_h,
                                                  float* __restrict__ out_z) {
    __shared__ float tlds[64][65];
    const int tid  = threadIdx.x;
    const int lane = tid & 63;
    const int wv   = tid >> 6;
    const int wg   = blockIdx.x;

#pragma unroll 1
    for (int tt = 0; tt < 2; ++tt) {
        const int t = wg * 2 + tt;
#pragma unroll 1
        for (int l = 0; l < 3; ++l) {
            const float* __restrict__ slot = hAll + ((size_t)(t + 1) * 3 + l) * SLOTF;
#pragma unroll 1
            for (int jc = 0; jc < 4; ++jc) {
                __syncthreads();
                {   // load 64j x 64b chunk -> LDS (coalesced float4 x2)
                    const int f = tid * 8;
                    const int j = f >> 6;
                    const int b = f & 63;
                    const float* src = slot + (size_t)(jc * 64 + j) * 64 + b;
                    float4 v0 = *(const float4*)(src);
                    float4 v1 = *(const float4*)(src + 4);
                    float* d = &tlds[j][b];
                    d[0] = v0.x; d[1] = v0.y; d[2] = v0.z; d[3] = v0.w;
                    d[4] = v1.x; d[5] = v1.y; d[6] = v1.z; d[7] = v1.w;
                }
                __syncthreads();
#pragma unroll
                for (int it = 0; it < 8; ++it) {
                    const int b = wv + it * 8;
                    out_h[((size_t)b * Tt + t) * (3 * Hh) + l * 256 + jc * 64 + lane]
                        = tlds[lane][b];
                }
            }
        }
    }
    if (wg == 0) {
        for (int f = tid; f < Bb * Tt * 3; f += 512) {
            const int b  = f / (Tt * 3);
            const int r  = f % (Tt * 3);
            const int t2 = r / 3;
            const int l2 = r % 3;
            const unsigned long long m = zA[(size_t)((t2 + 1) * 3 + l2) * ZSTR];
            out_z[f] = (float)((m >> b) & 1ull);
        }
    }
}

extern "C" void kernel_launch(void* const* d_in, const int* in_sizes, int n_in,
                              void* d_out, int out_size, void* d_ws, size_t ws_size,
                              hipStream_t stream) {
    (void)in_sizes; (void)n_in; (void)out_size;

    const float* x = (const float*)d_in[0];
    // dict order: x, Wb0,Wr0,Wt0,b0, Wb1,Wr1,Wt1,b1, Wb2,Wr2,Wt2,b2
    const float* biases[3] = { (const float*)d_in[4], (const float*)d_in[8],
                               (const float*)d_in[12] };
    float* wsf = (float*)d_ws;

    // ws layout (floats)
    const size_t OFF_CT   = 8 * (size_t)MATF;            // c ping-pong [2][3][16384]
    const size_t OFF_ZA   = OFF_CT + 2 * 3 * Hh * Bb;    // 1539 z masks x 64 floats
    const size_t OFF_HALL = OFF_ZA + (size_t)1539 * 64;  // 513*3 slots x SLOTF
    const size_t OFF_XT   = OFF_HALL + (size_t)513 * 3 * SLOTF;
    const size_t OFF_END  = OFF_XT + (size_t)Tt * Hh * Bb;

    float* WT   = wsf;
    float* cT   = wsf + OFF_CT;
    unsigned long long* zA = (unsigned long long*)(wsf + OFF_ZA);
    float* hAll = wsf + OFF_HALL;
    float* xT   = wsf + OFF_XT;

    const bool canSlots = ws_size >= OFF_XT * sizeof(float);
    const bool canXT    = ws_size >= OFF_END * sizeof(float);
    if (!canSlots) return;   // harness ws proven >= 110MB in r5..r10

    // Zero mutable state: c, z masks, first 6 h slots (zero initial state).
    hipMemsetAsync(cT, 0, (OFF_HALL - OFF_CT) * sizeof(float), stream);
    hipMemsetAsync(hAll, 0, (size_t)6 * SLOTF * sizeof(float), stream);

    Ptrs8 ps;
    const int mi[8] = { 1, 2, 3, 5, 6, 7, 9, 10 };  // Wb0,Wr0,Wt0,Wb1,Wr1,Wt1,Wb2,Wr2
    for (int i = 0; i < 8; ++i) ps.p[i] = (const float*)d_in[mi[i]];
    transpose_w<<<dim3(256, 8), 256, 0, stream>>>(ps, WT);
    if (canXT) transpose_x<<<512, 256, 0, stream>>>(x, xT);

    float* out_h = (float*)d_out;
    float* out_z = out_h + (size_t)Bb * Tt * (3 * Hh);

    const int wmb[3] = { 0, 3, 6 };
    const int wmr[3] = { 1, 4, 7 };
    const int wmt[3] = { 2, 5, -1 };

    auto slot = [&](int tIdx, int ll) { return hAll + ((size_t)tIdx * 3 + ll) * SLOTF; };
    auto makeP = [&](int t, int l) {
        StageP P;
        P.bot  = (l == 0) ? (canXT ? xT + (size_t)t * Hh * 64 : nullptr)
                          : slot(t + 1, l - 1);
        P.x    = (l == 0) ? x : nullptr;
        P.h    = slot(t, l);
        P.top  = (l < 2) ? slot(t, l + 1) : nullptr;
        P.Wb   = WT + (size_t)wmb[l] * MATF;
        P.Wr   = WT + (size_t)wmr[l] * MATF;
        P.Wt   = (l < 2) ? WT + (size_t)wmt[l] * MATF : nullptr;
        P.bias = biases[l];
        P.c_rd = cT + (size_t)((t & 1) * 3 + l) * (Hh * Bb);
        P.c_wr = cT + (size_t)(((t & 1) ^ 1) * 3 + l) * (Hh * Bb);
        P.zm0  = &zA[(size_t)(t * 3 + l) * ZSTR];
        P.zm1  = (l > 0) ? &zA[(size_t)((t + 1) * 3 + l - 1) * ZSTR] : nullptr;
        P.h_wr = slot(t + 1, l);
        P.zm_wr = &zA[(size_t)((t + 1) * 3 + l) * ZSTR];
        P.t    = t;
        return P;
    };

    // Diagonal schedule k = 2t + l, k = 0..1024 (DAG critical path):
    //  k even: {l0@k/2 (if k<=1022)} + {l2@(k/2-1) (if k>=2)} in one launch.
    //  k odd : l1@(k-1)/2.
    for (int k = 0; k <= 2 * (Tt - 1) + 2; ++k) {
        if ((k & 1) == 0) {
            const bool hasA = (k <= 2 * (Tt - 1));    // l0 @ t=k/2
            const bool hasB = (k >= 2);               // l2 @ t=k/2-1
            if (hasA && hasB) {
                stage2_kernel<<<512, 512, 0, stream>>>(makeP(k / 2, 0), makeP(k / 2 - 1, 2));
            } else if (hasA) {
                stage1_kernel<<<256, 512, 0, stream>>>(makeP(k / 2, 0));
            } else {
                stage1_kernel<<<256, 512, 0, stream>>>(makeP(k / 2 - 1, 2));
            }
        } else {
            stage1_kernel<<<256, 512, 0, stream>>>(makeP((k - 1) / 2, 1));
        }
    }
    expand_out<<<256, 512, 0, stream>>>(hAll, zA, out_h, out_z);
}